// Round 3
// baseline (2973.660 us; speedup 1.0000x reference)
//
#include <hip/hip_runtime.h>

#define LB __launch_bounds__(256)

// problem sizes
static constexpr int  B_  = 4, H_ = 4, T_ = 64, HT_ = 256, D_ = 256, E_ = 1024, L_ = 768;
static constexpr int  NI_ = 21760, NV_ = 256;
static constexpr long OUTV_N = 22282240L;   // 4*21760*256
static constexpr float SC_ = 0.0625f;       // HEAD_DIM^-0.5

// workspace offsets (in floats).  total = 30,187,264 floats = 115.2 MiB
static constexpr long WS_KF  = 0;        // K projection      [256][1024]
static constexpr long WS_VL  = 262144;   // val_l projection  [256][1024]
static constexpr long WS_CM  = 524288;   // Cmat              [4][256][256]
static constexpr long WS_CB  = 786432;   // cbias             [4][256]
static constexpr long WS_UU  = 787456;   // U                 [4][256][256]
static constexpr long WS_W2  = 1049600;  // W2                [768][1024]
static constexpr long WS_B2  = 1836032;  // bias2             [768]
static constexpr long WS_WT  = 1836800;  // Wt (conv w transposed) [64*9][64]
static constexpr long WS_CMX = 1873664;  // col max           [1024]
static constexpr long WS_CSM = 1874688;  // col sum           [1024]
static constexpr long WS_G   = 1875712;  // G = p_l @ v       [4][256][256]
static constexpr long WS_G2  = 2137856;  // G transposed      [4][64][1024]
static constexpr long WS_LO  = 2400000;  // conv outputs      [16][64][5376]
static constexpr long WS_AW  = 7905024;  // attention map     [4][256][21760]

// ---------------------------------------------------------------------------
// generic 64x64-tile GEMM, NT: C[m][n] = scale*sum_k A[m*lda+k]*B[n*ldb+k] + biasM[m] + biasN[n]
// z decomposition: zb = z>>2, zh = z&3 (for Z=4 launches zh==z)
__global__ LB void gemm_nt(const float* __restrict__ A, int lda, long aZb, long aZh,
                           const float* __restrict__ Bm, int ldb, long bZb, long bZh,
                           float* __restrict__ C, int ldo, long oZb, long oZh,
                           int K, float scale,
                           const float* __restrict__ biasM, long bmZh,
                           const float* __restrict__ biasN)
{
    const int z = blockIdx.z, zb = z >> 2, zh = z & 3;
    A  += (long)zb * aZb + (long)zh * aZh;
    Bm += (long)zb * bZb + (long)zh * bZh;
    C  += (long)zb * oZb + (long)zh * oZh;
    if (biasM) biasM += (long)zh * bmZh;
    const int m0 = blockIdx.y * 64, n0 = blockIdx.x * 64;
    __shared__ float As[64][36];
    __shared__ float Bs[64][36];
    const int tid = threadIdx.x;
    const int tm = (tid >> 4) * 4, tn = (tid & 15) * 4;
    float acc[4][4] = {};
    for (int kb = 0; kb < K; kb += 32) {
        __syncthreads();
        #pragma unroll
        for (int idx = tid; idx < 2048; idx += 256) {
            int r = idx >> 5, c = idx & 31;
            As[r][c] = A[(long)(m0 + r) * lda + kb + c];
            Bs[r][c] = Bm[(long)(n0 + r) * ldb + kb + c];
        }
        __syncthreads();
        #pragma unroll
        for (int kk = 0; kk < 32; kk += 4) {
            float4 a0 = *(const float4*)&As[tm + 0][kk];
            float4 a1 = *(const float4*)&As[tm + 1][kk];
            float4 a2 = *(const float4*)&As[tm + 2][kk];
            float4 a3 = *(const float4*)&As[tm + 3][kk];
            float4 b0 = *(const float4*)&Bs[tn + 0][kk];
            float4 b1 = *(const float4*)&Bs[tn + 1][kk];
            float4 b2 = *(const float4*)&Bs[tn + 2][kk];
            float4 b3 = *(const float4*)&Bs[tn + 3][kk];
#define NT_ROW(m, av) \
            acc[m][0] += av.x*b0.x + av.y*b0.y + av.z*b0.z + av.w*b0.w; \
            acc[m][1] += av.x*b1.x + av.y*b1.y + av.z*b1.z + av.w*b1.w; \
            acc[m][2] += av.x*b2.x + av.y*b2.y + av.z*b2.z + av.w*b2.w; \
            acc[m][3] += av.x*b3.x + av.y*b3.y + av.z*b3.z + av.w*b3.w;
            NT_ROW(0, a0) NT_ROW(1, a1) NT_ROW(2, a2) NT_ROW(3, a3)
#undef NT_ROW
        }
    }
    float4 bn = make_float4(0.f, 0.f, 0.f, 0.f);
    if (biasN) bn = *(const float4*)&biasN[n0 + tn];
    #pragma unroll
    for (int im = 0; im < 4; ++im) {
        float bm = biasM ? biasM[m0 + tm + im] : 0.f;
        float4 r;
        r.x = scale * acc[im][0] + bm + bn.x;
        r.y = scale * acc[im][1] + bm + bn.y;
        r.z = scale * acc[im][2] + bm + bn.z;
        r.w = scale * acc[im][3] + bm + bn.w;
        *(float4*)&C[(long)(m0 + tm + im) * ldo + n0 + tn] = r;
    }
}

// generic 64x64-tile GEMM, NN: C[m][n] = scale*sum_k A[m*lda+k]*B[k*ldb+n]
__global__ LB void gemm_nn(const float* __restrict__ A, int lda, long aZb, long aZh,
                           const float* __restrict__ Bm, int ldb, long bZb, long bZh,
                           float* __restrict__ C, int ldo, long oZb, long oZh,
                           int K, float scale)
{
    const int z = blockIdx.z, zb = z >> 2, zh = z & 3;
    A  += (long)zb * aZb + (long)zh * aZh;
    Bm += (long)zb * bZb + (long)zh * bZh;
    C  += (long)zb * oZb + (long)zh * oZh;
    const int m0 = blockIdx.y * 64, n0 = blockIdx.x * 64;
    __shared__ float As[64][36];
    __shared__ float Bs[32][68];
    const int tid = threadIdx.x;
    const int tm = (tid >> 4) * 4, tn = (tid & 15) * 4;
    float acc[4][4] = {};
    for (int kb = 0; kb < K; kb += 32) {
        __syncthreads();
        #pragma unroll
        for (int idx = tid; idx < 2048; idx += 256) {
            int r = idx >> 5, c = idx & 31;
            As[r][c] = A[(long)(m0 + r) * lda + kb + c];
            int r2 = idx >> 6, c2 = idx & 63;
            Bs[r2][c2] = Bm[(long)(kb + r2) * ldb + n0 + c2];
        }
        __syncthreads();
        #pragma unroll
        for (int kk = 0; kk < 32; kk += 4) {
            float4 a0 = *(const float4*)&As[tm + 0][kk];
            float4 a1 = *(const float4*)&As[tm + 1][kk];
            float4 a2 = *(const float4*)&As[tm + 2][kk];
            float4 a3 = *(const float4*)&As[tm + 3][kk];
            float4 b0 = *(const float4*)&Bs[kk + 0][tn];
            float4 b1 = *(const float4*)&Bs[kk + 1][tn];
            float4 b2 = *(const float4*)&Bs[kk + 2][tn];
            float4 b3 = *(const float4*)&Bs[kk + 3][tn];
#define NN_ROW(m, av) \
            acc[m][0] += av.x*b0.x + av.y*b1.x + av.z*b2.x + av.w*b3.x; \
            acc[m][1] += av.x*b0.y + av.y*b1.y + av.z*b2.y + av.w*b3.y; \
            acc[m][2] += av.x*b0.z + av.y*b1.z + av.z*b2.z + av.w*b3.z; \
            acc[m][3] += av.x*b0.w + av.y*b1.w + av.z*b2.w + av.w*b3.w;
            NN_ROW(0, a0) NN_ROW(1, a1) NN_ROW(2, a2) NN_ROW(3, a3)
#undef NN_ROW
        }
    }
    #pragma unroll
    for (int im = 0; im < 4; ++im) {
        float4 r;
        r.x = scale * acc[im][0];
        r.y = scale * acc[im][1];
        r.z = scale * acc[im][2];
        r.w = scale * acc[im][3];
        *(float4*)&C[(long)(m0 + tm + im) * ldo + n0 + tn] = r;
    }
}

// cbias[b][ht] = SCALE * sum_d vp_b[h*256+d] * KF[(b*64+t)*1024 + h*256+d]
__global__ LB void k_cbias(const float* __restrict__ KF, const float* __restrict__ vp_b,
                           float* __restrict__ cb)
{
    int idx = blockIdx.x * 256 + threadIdx.x;      // 0..1023
    int b = idx >> 8, ht = idx & 255, h = ht >> 6, t = ht & 63;
    const float* kr = KF + (long)(b * 64 + t) * 1024 + h * 256;
    const float* br = vp_b + h * 256;
    float s = 0.f;
    for (int d = 0; d < 256; d += 4) {
        float4 a = *(const float4*)&kr[d];
        float4 c = *(const float4*)&br[d];
        s += a.x*c.x + a.y*c.y + a.z*c.z + a.w*c.w;
    }
    cb[idx] = s * SC_;
}

// bias2[o] = olp_b[o] + sum_hd olp_w[o*1024+hd]*vvp_b[hd]
__global__ LB void k_bias2(const float* __restrict__ olp_w, const float* __restrict__ olp_b,
                           const float* __restrict__ vvp_b, float* __restrict__ b2)
{
    int o = blockIdx.x * 256 + threadIdx.x;        // 0..767
    const float* wr = olp_w + (long)o * 1024;
    float s = olp_b[o];
    for (int k = 0; k < 1024; k += 4) {
        float4 a = *(const float4*)&wr[k];
        float4 c = *(const float4*)&vvp_b[k];
        s += a.x*c.x + a.y*c.y + a.z*c.z + a.w*c.w;
    }
    b2[o] = s;
}

// transpose conv weights: Wt[(ti*9+tap)*64 + to] = down_w[((to*64+ti)*9 + tap)]
__global__ LB void k_wt(const float* __restrict__ dw, float* __restrict__ Wt)
{
    int idx = blockIdx.x * 256 + threadIdx.x;      // < 36864
    int to = idx / 576, rem = idx - to * 576;
    int ti = rem / 9, tap = rem - ti * 9;
    Wt[(ti * 9 + tap) * 64 + to] = dw[idx];
}

// stride-2 3x3 conv, 64ch->64ch, over pyramid levels 1..3 (inputs are ORIGINAL aw levels 0..2)
__global__ LB void k_conv(const float* __restrict__ aw, const float* __restrict__ Wt,
                          const float* __restrict__ down_b, float* __restrict__ lo)
{
    __shared__ float ins[16][17][36];
    const int bx = blockIdx.x, bh = blockIdx.y;
    int w_out, w_in, in_off, lo_off, ty, tx;
    if (bx < 32)      { w_out = 64; w_in = 128; in_off = 0;     lo_off = 0;    ty = bx >> 2;       tx = bx & 3; }
    else if (bx < 40) { w_out = 32; w_in = 64;  in_off = 16384; lo_off = 4096; int e = bx - 32; ty = e >> 1; tx = e & 1; }
    else              { w_out = 16; w_in = 32;  in_off = 20480; lo_off = 5120; ty = bx - 40;       tx = 0; }
    const int y0 = ty * 8, x0 = tx * 16;
    const int tid = threadIdx.x;
    const int to0 = (tid & 15) * 4;
    const int pg = tid >> 4;          // 0..15
    const int py = pg & 7;            // row within 8-row tile
    const int xbase = (pg >> 3) * 8;  // 0 or 8
    const float* in_base = aw + (long)(bh >> 2) * HT_ * NI_ + (long)((bh & 3) * 64) * NI_ + in_off;
    float acc[4][8] = {};
    for (int tc = 0; tc < 64; tc += 16) {
        __syncthreads();
        for (int idx = tid; idx < 16 * 561; idx += 256) {
            int ti = idx / 561, rem = idx - ti * 561;
            int r = rem / 33, c = rem - r * 33;
            int gy = 2 * y0 - 1 + r, gx = 2 * x0 - 1 + c;
            float vv = 0.f;
            if (gy >= 0 && gy < w_in && gx >= 0 && gx < w_in)
                vv = in_base[(long)(tc + ti) * NI_ + gy * w_in + gx];
            ins[ti][r][c] = vv;
        }
        __syncthreads();
        for (int ti = 0; ti < 16; ++ti) {
            const int tig = tc + ti;
            #pragma unroll
            for (int ky = 0; ky < 3; ++ky) {
                const int r = 2 * py + ky;
                const float* rowp = &ins[ti][r][2 * xbase];
                float rv[20];
                #pragma unroll
                for (int q = 0; q < 5; ++q) {
                    float4 f = *(const float4*)(rowp + 4 * q);
                    rv[4*q+0] = f.x; rv[4*q+1] = f.y; rv[4*q+2] = f.z; rv[4*q+3] = f.w;
                }
                #pragma unroll
                for (int kx = 0; kx < 3; ++kx) {
                    float4 w4 = *(const float4*)&Wt[(tig * 9 + ky * 3 + kx) * 64 + to0];
                    #pragma unroll
                    for (int x = 0; x < 8; ++x) {
                        float iv = rv[2 * x + kx];
                        acc[0][x] += iv * w4.x;
                        acc[1][x] += iv * w4.y;
                        acc[2][x] += iv * w4.z;
                        acc[3][x] += iv * w4.w;
                    }
                }
            }
        }
    }
    const long lo_base = (long)bh * 64 * 5376;
    #pragma unroll
    for (int j = 0; j < 4; ++j) {
        float bias = down_b[to0 + j];
        float* op = lo + lo_base + (long)(to0 + j) * 5376 + lo_off + (y0 + py) * w_out + x0 + xbase;
        #pragma unroll
        for (int x = 0; x < 8; ++x) op[x] = acc[j][x] + bias;
    }
}

// in-place pyramid update for one level (must be launched lvl 0,1,2,3 in order)
__global__ LB void k_update(float* __restrict__ aw, const float* __restrict__ lo,
                            const float* __restrict__ simp, int lvl, int w_out, int off_out,
                            int w_src, int off_src, int lo_off)
{
    const int bht = blockIdx.y;
    const int pix = blockIdx.x * 256 + threadIdx.x;
    float* base = aw + (long)bht * NI_;
    float cur = base[off_out + pix];
    float alpha = simp[0];
    float upd = 0.f;
    if (lvl < 3) {   // top-down: bilinear 2x upsample of coarser level (half-pixel, clamped)
        int y = pix / w_out, x = pix - y * w_out;
        int j0 = (y - 1) >> 1; float wy = (y & 1) ? 0.25f : 0.75f;
        int i0 = (x - 1) >> 1; float wx = (x & 1) ? 0.25f : 0.75f;
        int j0c = j0 < 0 ? 0 : j0, j1c = j0 + 1 < w_src ? j0 + 1 : w_src - 1;
        int i0c = i0 < 0 ? 0 : i0, i1c = i0 + 1 < w_src ? i0 + 1 : w_src - 1;
        const float* src = base + off_src;
        float v00 = src[j0c * w_src + i0c], v01 = src[j0c * w_src + i1c];
        float v10 = src[j1c * w_src + i0c], v11 = src[j1c * w_src + i1c];
        float up = (1.f - wy) * ((1.f - wx) * v00 + wx * v01) + wy * ((1.f - wx) * v10 + wx * v11);
        upd += alpha * (up - cur);
    }
    if (lvl > 0) {   // bottom-up: conv-downsampled finer level
        float lov = lo[(long)bht * 5376 + lo_off + pix];
        upd += alpha * (lov - cur);
    }
    base[off_out + pix] = cur + 0.5f * upd;
}

// per-(b,ht) row max and sum of exp over all 21760 image positions (for p_l)
__global__ LB void k_colstats(const float* __restrict__ aw, float* __restrict__ cmax,
                              float* __restrict__ csum)
{
    const int bht = blockIdx.x;
    const float* row = aw + (long)bht * NI_;
    const int tid = threadIdx.x;
    float m = -3.0e38f, s = 0.f;
    for (int i = tid; i < NI_; i += 256) {
        float vv = row[i];
        if (vv > m) { s *= __expf(m - vv); m = vv; }
        s += __expf(vv - m);
    }
    for (int off = 32; off > 0; off >>= 1) {
        float om = __shfl_down(m, off, 64);
        float os = __shfl_down(s, off, 64);
        float M = fmaxf(m, om);
        s = s * __expf(m - M) + os * __expf(om - M);
        m = M;
    }
    __shared__ float sm[4], ss[4];
    int wave = tid >> 6;
    if ((tid & 63) == 0) { sm[wave] = m; ss[wave] = s; }
    __syncthreads();
    if (tid == 0) {
        m = sm[0]; s = ss[0];
        for (int w = 1; w < 4; ++w) {
            float M = fmaxf(m, sm[w]);
            s = s * __expf(m - M) + ss[w] * __expf(sm[w] - M);
            m = M;
        }
        cmax[bht] = m; csum[bht] = s;
    }
}

// G[b][ht][c] += sum_i softmax_i(aw)[ht][i] * v[b][i][c]   (split-K over i, f32 atomics)
__global__ LB void k_plv(const float* __restrict__ aw, const float* __restrict__ v,
                         const float* __restrict__ cmax, const float* __restrict__ csum,
                         float* __restrict__ G)
{
    const int b = blockIdx.z, htg = blockIdx.y;
    const int i0 = blockIdx.x * 640;
    const int tid = threadIdx.x;
    __shared__ float as[64][37];
    __shared__ float vs[32][256];
    __shared__ float cm[64], ci[64];
    if (tid < 64) {
        int ht = htg * 64 + tid;
        cm[tid] = cmax[b * 256 + ht];
        ci[tid] = 1.f / csum[b * 256 + ht];
    }
    const int cg4 = (tid & 15) * 4;
    const int hg4 = (tid >> 4) * 4;
    float acc[4][16] = {};
    const float* awb = aw + (long)b * HT_ * NI_ + (long)(htg * 64) * NI_;
    const float* vb = v + (long)b * NI_ * 256;
    __syncthreads();
    for (int ii = 0; ii < 640; ii += 32) {
        __syncthreads();
        for (int idx = tid; idx < 2048; idx += 256) {
            int r = idx >> 5, c = idx & 31;
            float val = awb[(long)r * NI_ + i0 + ii + c];
            as[r][c] = __expf(val - cm[r]) * ci[r];
        }
        for (int idx = tid; idx < 8192; idx += 256) {
            int r = idx >> 8, c = idx & 255;
            vs[r][c] = vb[(long)(i0 + ii + r) * 256 + c];
        }
        __syncthreads();
        for (int i = 0; i < 32; ++i) {
            float a0 = as[hg4 + 0][i], a1 = as[hg4 + 1][i], a2 = as[hg4 + 2][i], a3 = as[hg4 + 3][i];
            #pragma unroll
            for (int q = 0; q < 4; ++q) {
                float4 vv = *(const float4*)&vs[i][cg4 + 64 * q];
                acc[0][q*4+0] += a0*vv.x; acc[0][q*4+1] += a0*vv.y; acc[0][q*4+2] += a0*vv.z; acc[0][q*4+3] += a0*vv.w;
                acc[1][q*4+0] += a1*vv.x; acc[1][q*4+1] += a1*vv.y; acc[1][q*4+2] += a1*vv.z; acc[1][q*4+3] += a1*vv.w;
                acc[2][q*4+0] += a2*vv.x; acc[2][q*4+1] += a2*vv.y; acc[2][q*4+2] += a2*vv.z; acc[2][q*4+3] += a2*vv.w;
                acc[3][q*4+0] += a3*vv.x; acc[3][q*4+1] += a3*vv.y; acc[3][q*4+2] += a3*vv.z; acc[3][q*4+3] += a3*vv.w;
            }
        }
    }
    #pragma unroll
    for (int j = 0; j < 4; ++j)
        #pragma unroll
        for (int q = 0; q < 4; ++q)
            #pragma unroll
            for (int c = 0; c < 4; ++c)
                atomicAdd(&G[((long)b * 256 + htg * 64 + hg4 + j) * 256 + cg4 + 64 * q + c],
                          acc[j][q * 4 + c]);
}

// fused per-head row softmax (over 64 txt tokens) + GEMM with U + ovp_b -> out_v (final)
__global__ LB void k_attnv(const float* __restrict__ aw, const float* __restrict__ U,
                           const float* __restrict__ ovp_b, float* __restrict__ outv)
{
    const int b = blockIdx.y;
    const int i0 = blockIdx.x * 32;
    const int tid = threadIdx.x;
    __shared__ float tile[256][36];
    const float* awb = aw + (long)b * HT_ * NI_;
    for (int idx = tid; idx < 8192; idx += 256) {
        int r = idx >> 5, c = idx & 31;
        tile[r][c] = awb[(long)r * NI_ + i0 + c];
    }
    __syncthreads();
    if (tid < 128) {      // softmax over t within each head, per image position
        int h = tid >> 5, i = tid & 31;
        float m = -3.0e38f;
        for (int t = 0; t < 64; ++t) m = fmaxf(m, tile[h * 64 + t][i]);
        float s = 0.f;
        for (int t = 0; t < 64; ++t) {
            float e = __expf(tile[h * 64 + t][i] - m);
            tile[h * 64 + t][i] = e;
            s += e;
        }
        float inv = 1.f / s;
        for (int t = 0; t < 64; ++t) tile[h * 64 + t][i] *= inv;
    }
    __syncthreads();
    const int o0 = (tid & 15) * 16;
    const int il0 = (tid >> 4) * 2;
    float acc0[16] = {}, acc1[16] = {};
    const float* Ub = U + (long)b * 65536;
    for (int ht = 0; ht < 256; ++ht) {
        float2 p2 = *(const float2*)&tile[ht][il0];
        const float* ur = Ub + ht * 256 + o0;
        #pragma unroll
        for (int q = 0; q < 4; ++q) {
            float4 u4 = *(const float4*)(ur + 4 * q);
            acc0[q*4+0] += p2.x*u4.x; acc0[q*4+1] += p2.x*u4.y; acc0[q*4+2] += p2.x*u4.z; acc0[q*4+3] += p2.x*u4.w;
            acc1[q*4+0] += p2.y*u4.x; acc1[q*4+1] += p2.y*u4.y; acc1[q*4+2] += p2.y*u4.z; acc1[q*4+3] += p2.y*u4.w;
        }
    }
    #pragma unroll
    for (int il = 0; il < 2; ++il) {
        const float* a = il ? acc1 : acc0;
        long orow = ((long)b * NI_ + i0 + il0 + il) * 256;
        #pragma unroll
        for (int q = 0; q < 4; ++q) {
            float4 bv = *(const float4*)&ovp_b[o0 + 4 * q];
            float4 r;
            r.x = a[q*4+0] + bv.x; r.y = a[q*4+1] + bv.y; r.z = a[q*4+2] + bv.z; r.w = a[q*4+3] + bv.w;
            *(float4*)&outv[orow + o0 + 4 * q] = r;
        }
    }
}

// G2[b][t][h*256+c] = G[b][h*64+t][c]
__global__ LB void k_g2t(const float* __restrict__ G, float* __restrict__ G2)
{
    int idx = blockIdx.x * 256 + threadIdx.x;   // < 262144
    int b = idx >> 16, r = idx & 65535;
    int t = r >> 10, e = r & 1023;
    int h = e >> 8, c = e & 255;
    G2[idx] = G[(long)b * 65536 + (h * 64 + t) * 256 + c];
}

// ---------------------------------------------------------------------------
extern "C" void kernel_launch(void* const* d_in, const int* in_sizes, int n_in,
                              void* d_out, int out_size, void* d_ws, size_t ws_size,
                              hipStream_t stream)
{
    const float* v      = (const float*)d_in[0];
    const float* l      = (const float*)d_in[1];
    const float* simp   = (const float*)d_in[2];
    const float* vp_w   = (const float*)d_in[3];
    const float* vp_b   = (const float*)d_in[4];
    const float* lp_w   = (const float*)d_in[5];
    const float* lp_b   = (const float*)d_in[6];
    const float* vvp_w  = (const float*)d_in[7];
    const float* vvp_b  = (const float*)d_in[8];
    const float* vlp_w  = (const float*)d_in[9];
    const float* vlp_b  = (const float*)d_in[10];
    const float* ovp_w  = (const float*)d_in[11];
    const float* ovp_b  = (const float*)d_in[12];
    const float* olp_w  = (const float*)d_in[13];
    const float* olp_b  = (const float*)d_in[14];
    const float* down_w = (const float*)d_in[15];
    const float* down_b = (const float*)d_in[16];

    float* outv = (float*)d_out;
    float* outl = outv + OUTV_N;
    float* ws = (float*)d_ws;
    float* KF  = ws + WS_KF;
    float* VL  = ws + WS_VL;
    float* CM  = ws + WS_CM;
    float* CB  = ws + WS_CB;
    float* UU  = ws + WS_UU;
    float* W2  = ws + WS_W2;
    float* B2  = ws + WS_B2;
    float* WT  = ws + WS_WT;
    float* CMX = ws + WS_CMX;
    float* CSM = ws + WS_CSM;
    float* G   = ws + WS_G;
    float* G2  = ws + WS_G2;
    float* LO  = ws + WS_LO;
    float* AW  = ws + WS_AW;

    // 1/2: K = l@lp_w.T+lp_b, VL = l@vlp_w.T+vlp_b   -> [256 bt][1024 e]
    gemm_nt<<<dim3(16, 4, 1), 256, 0, stream>>>(l, 768, 0, 0, lp_w, 768, 0, 0,
                                                KF, 1024, 0, 0, 768, 1.f, nullptr, 0, lp_b);
    gemm_nt<<<dim3(16, 4, 1), 256, 0, stream>>>(l, 768, 0, 0, vlp_w, 768, 0, 0,
                                                VL, 1024, 0, 0, 768, 1.f, nullptr, 0, vlp_b);
    // 3: Cmat[b][ht][c] = SCALE*sum_d KF[bt][h*256+d]*vp_w[(h*256+d)*256+c]
    gemm_nn<<<dim3(4, 1, 16), 256, 0, stream>>>(KF, 1024, 65536, 256, vp_w, 256, 0, 65536,
                                                CM, 256, 65536, 16384, 256, SC_);
    // 4: cbias
    k_cbias<<<dim3(4), 256, 0, stream>>>(KF, vp_b, CB);
    // 5: U[b][ht][o] = sum_d VL[bt][h*256+d]*ovp_w[o*1024+h*256+d]
    gemm_nt<<<dim3(4, 1, 16), 256, 0, stream>>>(VL, 1024, 65536, 256, ovp_w, 1024, 0, 256,
                                                UU, 256, 65536, 16384, 256, 1.f, nullptr, 0, nullptr);
    // 6: W2[o][h*256+c] = sum_d olp_w[o*1024+h*256+d]*vvp_w[(h*256+d)*256+c]
    gemm_nn<<<dim3(4, 12, 4), 256, 0, stream>>>(olp_w, 1024, 0, 256, vvp_w, 256, 0, 65536,
                                                W2, 1024, 0, 256, 256, 1.f);
    // 7: bias2
    k_bias2<<<dim3(3), 256, 0, stream>>>(olp_w, olp_b, vvp_b, B2);
    // 8: AW[b][ht][i] = sum_c CM[b][ht][c]*v[b][i][c] + cbias[b][ht]
    gemm_nt<<<dim3(340, 4, 4), 256, 0, stream>>>(CM, 256, 0, 65536, v, 256, 0, (long)NI_ * 256,
                                                 AW, NI_, 0, (long)HT_ * NI_, 256, 1.f,
                                                 CB, 256, nullptr);
    // 9: conv weight transpose; 10: conv downsample levels 0..2 -> LO
    k_wt<<<dim3(144), 256, 0, stream>>>(down_w, WT);
    k_conv<<<dim3(42, 16), 256, 0, stream>>>(AW, WT, down_b, LO);
    // 11-14: in-place pyramid update, level 0..3 in order
    k_update<<<dim3(64, 1024), 256, 0, stream>>>(AW, LO, simp, 0, 128, 0,     64, 16384, 0);
    k_update<<<dim3(16, 1024), 256, 0, stream>>>(AW, LO, simp, 1, 64, 16384,  32, 20480, 0);
    k_update<<<dim3(4, 1024), 256, 0, stream>>>(AW, LO, simp, 2, 32, 20480,  16, 21504, 4096);
    k_update<<<dim3(1, 1024), 256, 0, stream>>>(AW, LO, simp, 3, 16, 21504,   0, 0,     5120);
    // 15: column-softmax stats (max / sumexp over i per (b,ht))
    k_colstats<<<dim3(1024), 256, 0, stream>>>(AW, CMX, CSM);
    // 16/17: G = p_l @ v  (zero + split-K atomics)
    hipMemsetAsync(G, 0, 262144 * sizeof(float), stream);
    k_plv<<<dim3(34, 4, 4), 256, 0, stream>>>(AW, v, CMX, CSM, G);
    // 18: out_v = softmax_rows(AW) @ U + ovp_b
    k_attnv<<<dim3(680, 4), 256, 0, stream>>>(AW, UU, ovp_b, outv);
    // 19/20: out_l = G2 @ W2.T + bias2
    k_g2t<<<dim3(1024), 256, 0, stream>>>(G, G2);
    gemm_nt<<<dim3(12, 1, 4), 256, 0, stream>>>(G2, 1024, 0, 65536, W2, 1024, 0, 0,
                                                outl, 768, 0, 49152, 1024, 1.f, nullptr, 0, B2);
}

// Round 5
// 1307.921 us; speedup vs baseline: 2.2736x; 2.2736x over previous
//
#include <hip/hip_runtime.h>

#define LB __launch_bounds__(256)

typedef __attribute__((ext_vector_type(8))) short bf16x8;
typedef __attribute__((ext_vector_type(4))) float f32x4;
typedef unsigned int  u32;
typedef unsigned short u16;

// problem sizes
static constexpr int  HT_ = 256, NI_ = 21760;
static constexpr long OUTV_N = 22282240L;   // 4*21760*256
static constexpr float SC_ = 0.0625f;       // HEAD_DIM^-0.5

// workspace offsets (in floats).  total ~13.7M floats = 52.2 MiB
// AW (4*256*21760 f32) lives in d_out's outv region (overwritten by attnv at the end).
static constexpr long WS_KF  = 0;        // K projection      [256][1024]
static constexpr long WS_VL  = 262144;   // val_l projection  [256][1024]
static constexpr long WS_CM  = 524288;   // Cmat f32          [4][256][256]
static constexpr long WS_CB  = 786432;   // cbias             [4][256]
static constexpr long WS_UU  = 787456;   // U f32             [4][256][256]
static constexpr long WS_W2  = 1049600;  // W2                [768][1024]
static constexpr long WS_B2  = 1836032;  // bias2             [768]
static constexpr long WS_WT  = 1836800;  // conv w transposed [64*9][64]
static constexpr long WS_CMX = 1873664;  // col max           [1024]
static constexpr long WS_CSM = 1874688;  // col sum           [1024]
static constexpr long WS_G   = 1875712;  // G = p_l @ v       [4][256][256]
static constexpr long WS_G2  = 2137856;  // G transposed      [4][64][1024]
static constexpr long WS_UT  = 2400000;  // U^T bf16          [4][256 o][256 ht] (131072 f32 slots)
static constexpr long WS_SH  = 2531072;  // shared region (11,141,120 f32 slots):
                                         //   phase A: LO conv outputs [16][64][5376] f32
                                         //   phase B: VBT bf16 [4][256 c][21760 i]
                                         //   phase C: PV  bf16 [4][21760 i][256 ht]

__device__ __forceinline__ u16 f2bf(float x){
    u32 u = __float_as_uint(x);
    return (u16)((u + 0x7FFFu + ((u >> 16) & 1u)) >> 16);
}
__device__ __forceinline__ float bf2f(u16 h){ return __uint_as_float(((u32)h) << 16); }

__device__ __forceinline__ f32x4 MFMA(bf16x8 a, bf16x8 b, f32x4 c){
    return __builtin_amdgcn_mfma_f32_16x16x32_bf16(a, b, c, 0, 0, 0);
}

// ---------------------------------------------------------------------------
// Generic MFMA NT GEMM: C[M][N] = A[M][K] * B[N][K]^T, block tile 64x256,
// 4 waves (2m x 2n), K staged 32/step.  LDS rows padded to 40 bf16 (2-way max).
// AMODE: 0 = A bf16 (Abf), 1 = A f32 with row-softmax transform exp(x-max)*inv,
//        2 = A f32 -> hi/lo bf16 split
// BMODE: 0 = B bf16 (Bbf), 2 = B f32 -> hi/lo split
// ATOMIC: 0 = store with biases, 1 = atomicAdd (no biases)
// grid: x = M/64, y = N/256, z = batch*zdiv (ks = z%zdiv, kstart = ks*nsteps*32)
template<int AMODE, int BMODE, int ATOMIC>
__global__ LB void mfma_nt(const u16* __restrict__ Abf, const float* __restrict__ Af,
                           int lda, long aBS,
                           const u16* __restrict__ Bbf, const float* __restrict__ Bf,
                           int ldb, long bBS,
                           float* __restrict__ C, int ldc, long cBS,
                           int nsteps, int zdiv,
                           const float* __restrict__ biasM, long bmBS,
                           const float* __restrict__ biasN,
                           const float* __restrict__ rmax, const float* __restrict__ rsum,
                           long rsBS)
{
    __shared__ u16 As [64 * 40];
    __shared__ u16 As2[(AMODE == 2) ? 64 * 40 : 8];
    __shared__ u16 Bs [256 * 40];
    __shared__ u16 Bs2[(BMODE == 2) ? 256 * 40 : 8];
    __shared__ float s_max[64], s_inv[64];

    const int tid = threadIdx.x;
    const int z = blockIdx.z;
    const int b = z / zdiv, ks = z - b * zdiv;
    const int m0 = blockIdx.x * 64;
    const int n0 = blockIdx.y * 256;
    const long kbase = (long)ks * nsteps * 32;

    const u16*   Ab  = Abf ? Abf + (long)b * aBS : nullptr;
    const float* Afp = Af  ? Af  + (long)b * aBS : nullptr;
    const u16*   Bb  = Bbf ? Bbf + (long)b * bBS : nullptr;
    const float* Bfp = Bf  ? Bf  + (long)b * bBS : nullptr;
    float* Cb = C + (long)b * cBS;
    const float* bM = biasM ? biasM + (long)b * bmBS : nullptr;

    if (AMODE == 1) {
        if (tid < 64) {
            s_max[tid] = rmax[(long)b * rsBS + m0 + tid];
            s_inv[tid] = 1.0f / rsum[(long)b * rsBS + m0 + tid];
        }
    }

    const int lane = tid & 63, wid = tid >> 6;
    const int wm = wid >> 1, wn = wid & 1;
    const int lr = lane & 15, lk = (lane >> 4) * 8;
    f32x4 acc[2][8] = {};

    const int ar = tid >> 2, aseg = tid & 3;   // A staging: row(0..63), 8-elem segment

    for (int it = 0; it < nsteps; ++it) {
        const long kk = kbase + (long)it * 32;
        __syncthreads();
        // ---- stage A: 64 rows x 32 elems
        if (AMODE == 0) {
            *(uint4*)&As[ar * 40 + aseg * 8] =
                *(const uint4*)(Ab + (long)(m0 + ar) * lda + kk + aseg * 8);
        } else if (AMODE == 2) {
            const float4* s = (const float4*)(Afp + (long)(m0 + ar) * lda + kk + aseg * 8);
            float4 x0 = s[0], x1 = s[1];
            float xs[8] = {x0.x, x0.y, x0.z, x0.w, x1.x, x1.y, x1.z, x1.w};
            u32 hw[4], lw[4];
            #pragma unroll
            for (int p = 0; p < 4; ++p) {
                u16 h0 = f2bf(xs[2*p]),   h1 = f2bf(xs[2*p+1]);
                u16 l0 = f2bf(xs[2*p]   - bf2f(h0));
                u16 l1 = f2bf(xs[2*p+1] - bf2f(h1));
                hw[p] = (u32)h0 | ((u32)h1 << 16);
                lw[p] = (u32)l0 | ((u32)l1 << 16);
            }
            uint4 th; th.x = hw[0]; th.y = hw[1]; th.z = hw[2]; th.w = hw[3];
            uint4 tl; tl.x = lw[0]; tl.y = lw[1]; tl.z = lw[2]; tl.w = lw[3];
            *(uint4*)&As [ar * 40 + aseg * 8] = th;
            *(uint4*)&As2[ar * 40 + aseg * 8] = tl;
        } else { // AMODE 1: softmax transform
            const float4* s = (const float4*)(Afp + (long)(m0 + ar) * lda + kk + aseg * 8);
            float4 x0 = s[0], x1 = s[1];
            float xs[8] = {x0.x, x0.y, x0.z, x0.w, x1.x, x1.y, x1.z, x1.w};
            float mm = s_max[ar], iv = s_inv[ar];
            u32 hw[4];
            #pragma unroll
            for (int p = 0; p < 4; ++p) {
                u16 h0 = f2bf(__expf(xs[2*p]   - mm) * iv);
                u16 h1 = f2bf(__expf(xs[2*p+1] - mm) * iv);
                hw[p] = (u32)h0 | ((u32)h1 << 16);
            }
            uint4 th; th.x = hw[0]; th.y = hw[1]; th.z = hw[2]; th.w = hw[3];
            *(uint4*)&As[ar * 40 + aseg * 8] = th;
        }
        // ---- stage B: 256 rows x 32 elems, row n = tid
        if (BMODE == 0) {
            const uint4* s = (const uint4*)(Bb + (long)(n0 + tid) * ldb + kk);
            uint4* d = (uint4*)&Bs[tid * 40];
            d[0] = s[0]; d[1] = s[1]; d[2] = s[2]; d[3] = s[3];
        } else {
            const float4* s = (const float4*)(Bfp + (long)(n0 + tid) * ldb + kk);
            float xs[32];
            #pragma unroll
            for (int q = 0; q < 8; ++q) {
                float4 t = s[q];
                xs[4*q] = t.x; xs[4*q+1] = t.y; xs[4*q+2] = t.z; xs[4*q+3] = t.w;
            }
            u32 hw[16], lw[16];
            #pragma unroll
            for (int p = 0; p < 16; ++p) {
                u16 h0 = f2bf(xs[2*p]),   h1 = f2bf(xs[2*p+1]);
                u16 l0 = f2bf(xs[2*p]   - bf2f(h0));
                u16 l1 = f2bf(xs[2*p+1] - bf2f(h1));
                hw[p] = (u32)h0 | ((u32)h1 << 16);
                lw[p] = (u32)l0 | ((u32)l1 << 16);
            }
            uint4* dh = (uint4*)&Bs [tid * 40];
            uint4* dl = (uint4*)&Bs2[tid * 40];
            #pragma unroll
            for (int g = 0; g < 4; ++g) {
                uint4 t; t.x = hw[4*g]; t.y = hw[4*g+1]; t.z = hw[4*g+2]; t.w = hw[4*g+3];
                dh[g] = t;
                uint4 t2; t2.x = lw[4*g]; t2.y = lw[4*g+1]; t2.z = lw[4*g+2]; t2.w = lw[4*g+3];
                dl[g] = t2;
            }
        }
        __syncthreads();
        // ---- compute
        bf16x8 a0 = *(const bf16x8*)&As[(wm * 32 + lr) * 40 + lk];
        bf16x8 a1 = *(const bf16x8*)&As[(wm * 32 + 16 + lr) * 40 + lk];
        bf16x8 a0l, a1l;
        if (AMODE == 2) {
            a0l = *(const bf16x8*)&As2[(wm * 32 + lr) * 40 + lk];
            a1l = *(const bf16x8*)&As2[(wm * 32 + 16 + lr) * 40 + lk];
        }
        #pragma unroll
        for (int nt = 0; nt < 8; ++nt) {
            const int boff = (wn * 128 + nt * 16 + lr) * 40 + lk;
            bf16x8 bh = *(const bf16x8*)&Bs[boff];
            acc[0][nt] = MFMA(a0, bh, acc[0][nt]);
            acc[1][nt] = MFMA(a1, bh, acc[1][nt]);
            if (AMODE == 2 && BMODE == 2) {
                bf16x8 bl = *(const bf16x8*)&Bs2[boff];
                acc[0][nt] = MFMA(a0,  bl, acc[0][nt]);
                acc[0][nt] = MFMA(a0l, bh, acc[0][nt]);
                acc[1][nt] = MFMA(a1,  bl, acc[1][nt]);
                acc[1][nt] = MFMA(a1l, bh, acc[1][nt]);
            }
        }
    }
    // ---- epilogue.  D: col = lane&15, row = (lane>>4)*4 + reg
    const int cr = (lane >> 4) * 4;
    #pragma unroll
    for (int mt = 0; mt < 2; ++mt) {
        #pragma unroll
        for (int nt = 0; nt < 8; ++nt) {
            f32x4 a = acc[mt][nt];
            const long gm0 = m0 + wm * 32 + mt * 16 + cr;
            const int  gn  = n0 + wn * 128 + nt * 16 + lr;
            float bn = (!ATOMIC && biasN) ? biasN[gn] : 0.f;
            #pragma unroll
            for (int rr = 0; rr < 4; ++rr) {
                if (ATOMIC) {
                    atomicAdd(Cb + (gm0 + rr) * (long)ldc + gn, a[rr]);
                } else {
                    float bm = bM ? bM[gm0 + rr] : 0.f;
                    Cb[(gm0 + rr) * (long)ldc + gn] = a[rr] + bm + bn;
                }
            }
        }
    }
}

// ---------------------------------------------------------------------------
// f32 64x64-tile GEMM, NT (bank-conflict-fixed lane map: cols tn + 16q)
__global__ LB void gemm_nt(const float* __restrict__ A, int lda, long aZb, long aZh,
                           const float* __restrict__ Bm, int ldb, long bZb, long bZh,
                           float* __restrict__ C, int ldo, long oZb, long oZh,
                           int K, float scale,
                           const float* __restrict__ biasM, long bmZh,
                           const float* __restrict__ biasN)
{
    const int z = blockIdx.z, zb = z >> 2, zh = z & 3;
    A  += (long)zb * aZb + (long)zh * aZh;
    Bm += (long)zb * bZb + (long)zh * bZh;
    C  += (long)zb * oZb + (long)zh * oZh;
    if (biasM) biasM += (long)zh * bmZh;
    const int m0 = blockIdx.y * 64, n0 = blockIdx.x * 64;
    __shared__ float As[64][36];
    __shared__ float Bs[64][36];
    const int tid = threadIdx.x;
    const int tm = (tid >> 4) * 4, tn = tid & 15;
    float acc[4][4] = {};
    for (int kb = 0; kb < K; kb += 32) {
        __syncthreads();
        #pragma unroll
        for (int idx = tid; idx < 2048; idx += 256) {
            int r = idx >> 5, c = idx & 31;
            As[r][c] = A[(long)(m0 + r) * lda + kb + c];
            Bs[r][c] = Bm[(long)(n0 + r) * ldb + kb + c];
        }
        __syncthreads();
        #pragma unroll
        for (int kk = 0; kk < 32; kk += 4) {
            float4 a0 = *(const float4*)&As[tm + 0][kk];
            float4 a1 = *(const float4*)&As[tm + 1][kk];
            float4 a2 = *(const float4*)&As[tm + 2][kk];
            float4 a3 = *(const float4*)&As[tm + 3][kk];
            float4 b0 = *(const float4*)&Bs[tn +  0][kk];
            float4 b1 = *(const float4*)&Bs[tn + 16][kk];
            float4 b2 = *(const float4*)&Bs[tn + 32][kk];
            float4 b3 = *(const float4*)&Bs[tn + 48][kk];
#define NT_ROW(m, av) \
            acc[m][0] += av.x*b0.x + av.y*b0.y + av.z*b0.z + av.w*b0.w; \
            acc[m][1] += av.x*b1.x + av.y*b1.y + av.z*b1.z + av.w*b1.w; \
            acc[m][2] += av.x*b2.x + av.y*b2.y + av.z*b2.z + av.w*b2.w; \
            acc[m][3] += av.x*b3.x + av.y*b3.y + av.z*b3.z + av.w*b3.w;
            NT_ROW(0, a0) NT_ROW(1, a1) NT_ROW(2, a2) NT_ROW(3, a3)
#undef NT_ROW
        }
    }
    #pragma unroll
    for (int im = 0; im < 4; ++im) {
        float bm = biasM ? biasM[m0 + tm + im] : 0.f;
        #pragma unroll
        for (int q = 0; q < 4; ++q) {
            float bn = biasN ? biasN[n0 + tn + 16*q] : 0.f;
            C[(long)(m0 + tm + im) * ldo + n0 + tn + 16*q] = scale * acc[im][q] + bm + bn;
        }
    }
}

// f32 64x64-tile GEMM, NN (unchanged — its LDS pattern is conflict-free)
__global__ LB void gemm_nn(const float* __restrict__ A, int lda, long aZb, long aZh,
                           const float* __restrict__ Bm, int ldb, long bZb, long bZh,
                           float* __restrict__ C, int ldo, long oZb, long oZh,
                           int K, float scale)
{
    const int z = blockIdx.z, zb = z >> 2, zh = z & 3;
    A  += (long)zb * aZb + (long)zh * aZh;
    Bm += (long)zb * bZb + (long)zh * bZh;
    C  += (long)zb * oZb + (long)zh * oZh;
    const int m0 = blockIdx.y * 64, n0 = blockIdx.x * 64;
    __shared__ float As[64][36];
    __shared__ float Bs[32][68];
    const int tid = threadIdx.x;
    const int tm = (tid >> 4) * 4, tn = (tid & 15) * 4;
    float acc[4][4] = {};
    for (int kb = 0; kb < K; kb += 32) {
        __syncthreads();
        #pragma unroll
        for (int idx = tid; idx < 2048; idx += 256) {
            int r = idx >> 5, c = idx & 31;
            As[r][c] = A[(long)(m0 + r) * lda + kb + c];
            int r2 = idx >> 6, c2 = idx & 63;
            Bs[r2][c2] = Bm[(long)(kb + r2) * ldb + n0 + c2];
        }
        __syncthreads();
        #pragma unroll
        for (int kk = 0; kk < 32; kk += 4) {
            float4 a0 = *(const float4*)&As[tm + 0][kk];
            float4 a1 = *(const float4*)&As[tm + 1][kk];
            float4 a2 = *(const float4*)&As[tm + 2][kk];
            float4 a3 = *(const float4*)&As[tm + 3][kk];
            float4 b0 = *(const float4*)&Bs[kk + 0][tn];
            float4 b1 = *(const float4*)&Bs[kk + 1][tn];
            float4 b2 = *(const float4*)&Bs[kk + 2][tn];
            float4 b3 = *(const float4*)&Bs[kk + 3][tn];
#define NN_ROW(m, av) \
            acc[m][0] += av.x*b0.x + av.y*b1.x + av.z*b2.x + av.w*b3.x; \
            acc[m][1] += av.x*b0.y + av.y*b1.y + av.z*b2.y + av.w*b3.y; \
            acc[m][2] += av.x*b0.z + av.y*b1.z + av.z*b2.z + av.w*b3.z; \
            acc[m][3] += av.x*b0.w + av.y*b1.w + av.z*b2.w + av.w*b3.w;
            NN_ROW(0, a0) NN_ROW(1, a1) NN_ROW(2, a2) NN_ROW(3, a3)
#undef NN_ROW
        }
    }
    #pragma unroll
    for (int im = 0; im < 4; ++im) {
        float4 r;
        r.x = scale * acc[im][0];
        r.y = scale * acc[im][1];
        r.z = scale * acc[im][2];
        r.w = scale * acc[im][3];
        *(float4*)&C[(long)(m0 + tm + im) * ldo + n0 + tn] = r;
    }
}

// cbias[b][ht] = SCALE * sum_d vp_b[h*256+d] * KF[(b*64+t)*1024 + h*256+d]
__global__ LB void k_cbias(const float* __restrict__ KF, const float* __restrict__ vp_b,
                           float* __restrict__ cb)
{
    int idx = blockIdx.x * 256 + threadIdx.x;      // 0..1023
    int b = idx >> 8, ht = idx & 255, h = ht >> 6, t = ht & 63;
    const float* kr = KF + (long)(b * 64 + t) * 1024 + h * 256;
    const float* br = vp_b + h * 256;
    float s = 0.f;
    for (int d = 0; d < 256; d += 4) {
        float4 a = *(const float4*)&kr[d];
        float4 c = *(const float4*)&br[d];
        s += a.x*c.x + a.y*c.y + a.z*c.z + a.w*c.w;
    }
    cb[idx] = s * SC_;
}

// bias2[o] = olp_b[o] + sum_hd olp_w[o*1024+hd]*vvp_b[hd]
__global__ LB void k_bias2(const float* __restrict__ olp_w, const float* __restrict__ olp_b,
                           const float* __restrict__ vvp_b, float* __restrict__ b2)
{
    int o = blockIdx.x * 256 + threadIdx.x;        // 0..767
    const float* wr = olp_w + (long)o * 1024;
    float s = olp_b[o];
    for (int k = 0; k < 1024; k += 4) {
        float4 a = *(const float4*)&wr[k];
        float4 c = *(const float4*)&vvp_b[k];
        s += a.x*c.x + a.y*c.y + a.z*c.z + a.w*c.w;
    }
    b2[o] = s;
}

// transpose conv weights: Wt[(ti*9+tap)*64 + to] = down_w[((to*64+ti)*9 + tap)]
__global__ LB void k_wt(const float* __restrict__ dw, float* __restrict__ Wt)
{
    int idx = blockIdx.x * 256 + threadIdx.x;      // < 36864
    int to = idx / 576, rem = idx - to * 576;
    int ti = rem / 9, tap = rem - ti * 9;
    Wt[(ti * 9 + tap) * 64 + to] = dw[idx];
}

// stride-2 3x3 conv, 64ch->64ch (inputs are ORIGINAL aw levels 0..2)
__global__ LB void k_conv(const float* __restrict__ aw, const float* __restrict__ Wt,
                          const float* __restrict__ down_b, float* __restrict__ lo)
{
    __shared__ float ins[16][17][36];
    const int bx = blockIdx.x, bh = blockIdx.y;
    int w_out, w_in, in_off, lo_off, ty, tx;
    if (bx < 32)      { w_out = 64; w_in = 128; in_off = 0;     lo_off = 0;    ty = bx >> 2;       tx = bx & 3; }
    else if (bx < 40) { w_out = 32; w_in = 64;  in_off = 16384; lo_off = 4096; int e = bx - 32; ty = e >> 1; tx = e & 1; }
    else              { w_out = 16; w_in = 32;  in_off = 20480; lo_off = 5120; ty = bx - 40;       tx = 0; }
    const int y0 = ty * 8, x0 = tx * 16;
    const int tid = threadIdx.x;
    const int to0 = (tid & 15) * 4;
    const int pg = tid >> 4;
    const int py = pg & 7;
    const int xbase = (pg >> 3) * 8;
    const float* in_base = aw + (long)(bh >> 2) * HT_ * NI_ + (long)((bh & 3) * 64) * NI_ + in_off;
    float acc[4][8] = {};
    for (int tc = 0; tc < 64; tc += 16) {
        __syncthreads();
        for (int idx = tid; idx < 16 * 561; idx += 256) {
            int ti = idx / 561, rem = idx - ti * 561;
            int r = rem / 33, c = rem - r * 33;
            int gy = 2 * y0 - 1 + r, gx = 2 * x0 - 1 + c;
            float vv = 0.f;
            if (gy >= 0 && gy < w_in && gx >= 0 && gx < w_in)
                vv = in_base[(long)(tc + ti) * NI_ + gy * w_in + gx];
            ins[ti][r][c] = vv;
        }
        __syncthreads();
        for (int ti = 0; ti < 16; ++ti) {
            const int tig = tc + ti;
            #pragma unroll
            for (int ky = 0; ky < 3; ++ky) {
                const int r = 2 * py + ky;
                const float* rowp = &ins[ti][r][2 * xbase];
                float rv[20];
                #pragma unroll
                for (int q = 0; q < 5; ++q) {
                    float4 f = *(const float4*)(rowp + 4 * q);
                    rv[4*q+0] = f.x; rv[4*q+1] = f.y; rv[4*q+2] = f.z; rv[4*q+3] = f.w;
                }
                #pragma unroll
                for (int kx = 0; kx < 3; ++kx) {
                    float4 w4 = *(const float4*)&Wt[(tig * 9 + ky * 3 + kx) * 64 + to0];
                    #pragma unroll
                    for (int x = 0; x < 8; ++x) {
                        float iv = rv[2 * x + kx];
                        acc[0][x] += iv * w4.x;
                        acc[1][x] += iv * w4.y;
                        acc[2][x] += iv * w4.z;
                        acc[3][x] += iv * w4.w;
                    }
                }
            }
        }
    }
    const long lo_base = (long)bh * 64 * 5376;
    #pragma unroll
    for (int j = 0; j < 4; ++j) {
        float bias = down_b[to0 + j];
        float* op = lo + lo_base + (long)(to0 + j) * 5376 + lo_off + (y0 + py) * w_out + x0 + xbase;
        #pragma unroll
        for (int x = 0; x < 8; ++x) op[x] = acc[j][x] + bias;
    }
}

// in-place pyramid update for one level (launched lvl 0,1,2,3 in order)
__global__ LB void k_update(float* __restrict__ aw, const float* __restrict__ lo,
                            const float* __restrict__ simp, int lvl, int w_out, int off_out,
                            int w_src, int off_src, int lo_off)
{
    const int bht = blockIdx.y;
    const int pix = blockIdx.x * 256 + threadIdx.x;
    float* base = aw + (long)bht * NI_;
    float cur = base[off_out + pix];
    float alpha = simp[0];
    float upd = 0.f;
    if (lvl < 3) {
        int y = pix / w_out, x = pix - y * w_out;
        int j0 = (y - 1) >> 1; float wy = (y & 1) ? 0.25f : 0.75f;
        int i0 = (x - 1) >> 1; float wx = (x & 1) ? 0.25f : 0.75f;
        int j0c = j0 < 0 ? 0 : j0, j1c = j0 + 1 < w_src ? j0 + 1 : w_src - 1;
        int i0c = i0 < 0 ? 0 : i0, i1c = i0 + 1 < w_src ? i0 + 1 : w_src - 1;
        const float* src = base + off_src;
        float v00 = src[j0c * w_src + i0c], v01 = src[j0c * w_src + i1c];
        float v10 = src[j1c * w_src + i0c], v11 = src[j1c * w_src + i1c];
        float up = (1.f - wy) * ((1.f - wx) * v00 + wx * v01) + wy * ((1.f - wx) * v10 + wx * v11);
        upd += alpha * (up - cur);
    }
    if (lvl > 0) {
        float lov = lo[(long)bht * 5376 + lo_off + pix];
        upd += alpha * (lov - cur);
    }
    base[off_out + pix] = cur + 0.5f * upd;
}

// per-(b,ht) row max and sumexp over 21760 image positions (for p_l)
__global__ LB void k_colstats(const float* __restrict__ aw, float* __restrict__ cmax,
                              float* __restrict__ csum)
{
    const int bht = blockIdx.x;
    const float* row = aw + (long)bht * NI_;
    const int tid = threadIdx.x;
    float m = -3.0e38f, s = 0.f;
    for (int i = tid; i < NI_; i += 256) {
        float vv = row[i];
        if (vv > m) { s *= __expf(m - vv); m = vv; }
        s += __expf(vv - m);
    }
    for (int off = 32; off > 0; off >>= 1) {
        float om = __shfl_down(m, off, 64);
        float os = __shfl_down(s, off, 64);
        float M = fmaxf(m, om);
        s = s * __expf(m - M) + os * __expf(om - M);
        m = M;
    }
    __shared__ float sm[4], ss[4];
    int wave = tid >> 6;
    if ((tid & 63) == 0) { sm[wave] = m; ss[wave] = s; }
    __syncthreads();
    if (tid == 0) {
        m = sm[0]; s = ss[0];
        for (int w = 1; w < 4; ++w) {
            float M = fmaxf(m, sm[w]);
            s = s * __expf(m - M) + ss[w] * __expf(sm[w] - M);
            m = M;
        }
        cmax[bht] = m; csum[bht] = s;
    }
}

// v[b][i][c] f32 -> VBT[b][c][i] bf16  (64x64 LDS tile transpose)
__global__ LB void k_cvt_vt(const float* __restrict__ v, u16* __restrict__ VBT)
{
    const int b = blockIdx.z, i0 = blockIdx.x * 64, c0 = blockIdx.y * 64;
    __shared__ u16 Ts[64][72];
    const int tid = threadIdx.x;
    const int r = tid >> 2, seg = tid & 3;
    const float4* s = (const float4*)(v + ((long)b * NI_ + i0 + r) * 256 + c0 + seg * 16);
    #pragma unroll
    for (int q = 0; q < 4; ++q) {
        float4 x = s[q];
        Ts[r][seg * 16 + 4*q + 0] = f2bf(x.x);
        Ts[r][seg * 16 + 4*q + 1] = f2bf(x.y);
        Ts[r][seg * 16 + 4*q + 2] = f2bf(x.z);
        Ts[r][seg * 16 + 4*q + 3] = f2bf(x.w);
    }
    __syncthreads();
    const int cr = tid >> 2, is = tid & 3;
    u32 o[8];
    #pragma unroll
    for (int j = 0; j < 8; ++j)
        o[j] = (u32)Ts[is * 16 + 2*j][cr] | ((u32)Ts[is * 16 + 2*j + 1][cr] << 16);
    uint4* d = (uint4*)(VBT + ((long)b * 256 + c0 + cr) * NI_ + i0 + is * 16);
    uint4 t0; t0.x = o[0]; t0.y = o[1]; t0.z = o[2]; t0.w = o[3];
    uint4 t1; t1.x = o[4]; t1.y = o[5]; t1.z = o[6]; t1.w = o[7];
    d[0] = t0; d[1] = t1;
}

// U[b][ht][o] f32 -> UT[b][o][ht] bf16
__global__ LB void k_t_u(const float* __restrict__ U, u16* __restrict__ UT)
{
    const int b = blockIdx.z, r0 = blockIdx.x * 64, c0 = blockIdx.y * 64;
    __shared__ float Fs[64][68];
    const int tid = threadIdx.x;
    const int r = tid >> 2, seg = tid & 3;
    const float4* s = (const float4*)(U + ((long)b * 256 + r0 + r) * 256 + c0 + seg * 16);
    #pragma unroll
    for (int q = 0; q < 4; ++q) *(float4*)&Fs[r][seg * 16 + 4*q] = s[q];
    __syncthreads();
    const int cr = tid >> 2, is = tid & 3;
    u32 o[8];
    #pragma unroll
    for (int j = 0; j < 8; ++j)
        o[j] = (u32)f2bf(Fs[is * 16 + 2*j][cr]) | ((u32)f2bf(Fs[is * 16 + 2*j + 1][cr]) << 16);
    uint4* d = (uint4*)(UT + ((long)b * 256 + c0 + cr) * 256 + r0 + is * 16);
    uint4 t0; t0.x = o[0]; t0.y = o[1]; t0.z = o[2]; t0.w = o[3];
    uint4 t1; t1.x = o[4]; t1.y = o[5]; t1.z = o[6]; t1.w = o[7];
    d[0] = t0; d[1] = t1;
}

// PV[b][i][ht] bf16 = softmax over t (within head) of AW[b][ht][i].  i-tile = 32.
__global__ LB void k_pv(const float* __restrict__ aw, u16* __restrict__ PV)
{
    const int b = blockIdx.y;
    const int i0 = blockIdx.x * 32;
    const int tid = threadIdx.x;
    __shared__ float tile[256][36];
    const float* awb = aw + (long)b * HT_ * NI_;
    const float4* src = (const float4*)(awb + (long)tid * NI_ + i0);
    #pragma unroll
    for (int q = 0; q < 8; ++q) *(float4*)&tile[tid][q * 4] = src[q];
    __syncthreads();
    if (tid < 128) {
        int h = tid >> 5, i = tid & 31;
        float m = -3.0e38f;
        for (int t = 0; t < 64; ++t) m = fmaxf(m, tile[h * 64 + t][i]);
        float s = 0.f;
        for (int t = 0; t < 64; ++t) s += __expf(tile[h * 64 + t][i] - m);
        float inv = 1.f / s;
        u32* dst = (u32*)(PV + ((long)b * NI_ + i0 + i) * 256 + h * 64);
        #pragma unroll 4
        for (int t = 0; t < 32; ++t) {
            u16 p0 = f2bf(__expf(tile[h * 64 + 2*t][i]     - m) * inv);
            u16 p1 = f2bf(__expf(tile[h * 64 + 2*t + 1][i] - m) * inv);
            dst[t] = (u32)p0 | ((u32)p1 << 16);
        }
    }
}

// G2[b][t][h*256+c] = G[b][h*64+t][c]
__global__ LB void k_g2t(const float* __restrict__ G, float* __restrict__ G2)
{
    int idx = blockIdx.x * 256 + threadIdx.x;   // < 262144
    int b = idx >> 16, r = idx & 65535;
    int t = r >> 10, e = r & 1023;
    int h = e >> 8, c = e & 255;
    G2[idx] = G[(long)b * 65536 + (h * 64 + t) * 256 + c];
}

// ---------------------------------------------------------------------------
extern "C" void kernel_launch(void* const* d_in, const int* in_sizes, int n_in,
                              void* d_out, int out_size, void* d_ws, size_t ws_size,
                              hipStream_t stream)
{
    const float* v      = (const float*)d_in[0];
    const float* l      = (const float*)d_in[1];
    const float* simp   = (const float*)d_in[2];
    const float* vp_w   = (const float*)d_in[3];
    const float* vp_b   = (const float*)d_in[4];
    const float* lp_w   = (const float*)d_in[5];
    const float* lp_b   = (const float*)d_in[6];
    const float* vvp_w  = (const float*)d_in[7];
    const float* vvp_b  = (const float*)d_in[8];
    const float* vlp_w  = (const float*)d_in[9];
    const float* vlp_b  = (const float*)d_in[10];
    const float* ovp_w  = (const float*)d_in[11];
    const float* ovp_b  = (const float*)d_in[12];
    const float* olp_w  = (const float*)d_in[13];
    const float* olp_b  = (const float*)d_in[14];
    const float* down_w = (const float*)d_in[15];
    const float* down_b = (const float*)d_in[16];

    float* outv = (float*)d_out;
    float* outl = outv + OUTV_N;
    float* AW   = outv;                 // AW lives in the outv region (dead before attnv writes)
    float* ws = (float*)d_ws;
    float* KF  = ws + WS_KF;
    float* VL  = ws + WS_VL;
    float* CM  = ws + WS_CM;
    float* CB  = ws + WS_CB;
    float* UU  = ws + WS_UU;
    float* W2  = ws + WS_W2;
    float* B2  = ws + WS_B2;
    float* WT  = ws + WS_WT;
    float* CMX = ws + WS_CMX;
    float* CSM = ws + WS_CSM;
    float* G   = ws + WS_G;
    float* G2  = ws + WS_G2;
    u16*   UT  = (u16*)(ws + WS_UT);
    float* LO  = ws + WS_SH;            // phase A
    u16*   VBT = (u16*)(ws + WS_SH);    // phase B (after updates)
    u16*   PV  = (u16*)(ws + WS_SH);    // phase C (after plv)

    // 1: projections K = l@lp_w.T+lp_b, VL = l@vlp_w.T+vlp_b  -> [256 bt][1024 e]
    gemm_nt<<<dim3(16, 4, 1), 256, 0, stream>>>(l, 768, 0, 0, lp_w, 768, 0, 0,
                                                KF, 1024, 0, 0, 768, 1.f, nullptr, 0, lp_b);
    gemm_nt<<<dim3(16, 4, 1), 256, 0, stream>>>(l, 768, 0, 0, vlp_w, 768, 0, 0,
                                                VL, 1024, 0, 0, 768, 1.f, nullptr, 0, vlp_b);
    // 2: small folded mats
    gemm_nn<<<dim3(4, 1, 16), 256, 0, stream>>>(KF, 1024, 65536, 256, vp_w, 256, 0, 65536,
                                                CM, 256, 65536, 16384, 256, SC_);
    k_cbias<<<dim3(4), 256, 0, stream>>>(KF, vp_b, CB);
    gemm_nt<<<dim3(4, 1, 16), 256, 0, stream>>>(VL, 1024, 65536, 256, ovp_w, 1024, 0, 256,
                                                UU, 256, 65536, 16384, 256, 1.f, nullptr, 0, nullptr);
    gemm_nn<<<dim3(4, 12, 4), 256, 0, stream>>>(olp_w, 1024, 0, 256, vvp_w, 256, 0, 65536,
                                                W2, 1024, 0, 256, 256, 1.f);
    k_bias2<<<dim3(3), 256, 0, stream>>>(olp_w, olp_b, vvp_b, B2);
    k_t_u<<<dim3(4, 4, 4), 256, 0, stream>>>(UU, UT);

    // 3: AW = CM @ v^T + cbias  (bf16x3 split MFMA; M=256, N=21760, K=256)
    mfma_nt<2, 2, 0><<<dim3(4, 85, 4), 256, 0, stream>>>(
        nullptr, CM, 256, 65536,
        nullptr, v, 256, (long)NI_ * 256,
        AW, NI_, (long)HT_ * NI_,
        8, 1, CB, 256, nullptr, nullptr, nullptr, 0);

    // 4: conv downsample + in-place pyramid update
    k_wt<<<dim3(144), 256, 0, stream>>>(down_w, WT);
    k_conv<<<dim3(42, 16), 256, 0, stream>>>(AW, WT, down_b, LO);
    k_update<<<dim3(64, 1024), 256, 0, stream>>>(AW, LO, simp, 0, 128, 0,     64, 16384, 0);
    k_update<<<dim3(16, 1024), 256, 0, stream>>>(AW, LO, simp, 1, 64, 16384,  32, 20480, 0);
    k_update<<<dim3(4, 1024), 256, 0, stream>>>(AW, LO, simp, 2, 32, 20480,  16, 21504, 4096);
    k_update<<<dim3(1, 1024), 256, 0, stream>>>(AW, LO, simp, 3, 16, 21504,   0, 0,     5120);

    // 5: column-softmax stats over i per (b,ht)
    k_colstats<<<dim3(1024), 256, 0, stream>>>(AW, CMX, CSM);

    // 6: v^T bf16 (overwrites LO region — LO is dead)
    k_cvt_vt<<<dim3(340, 4, 4), 256, 0, stream>>>(v, VBT);

    // 7: G = p_l @ v   (softmax-in-staging MFMA, split-K x17 with atomics)
    hipMemsetAsync(G, 0, 262144 * sizeof(float), stream);
    mfma_nt<1, 0, 1><<<dim3(4, 1, 68), 256, 0, stream>>>(
        nullptr, AW, NI_, (long)HT_ * NI_,
        VBT, nullptr, NI_, (long)256 * NI_,
        G, 256, 65536,
        40, 17, nullptr, 0, nullptr, CMX, CSM, 256);

    // 8: PV bf16 (overwrites VBT region — VBT is dead)
    k_pv<<<dim3(680, 4), 256, 0, stream>>>(AW, PV);

    // 9: out_v = PV @ UT^T + ovp_b  (MFMA; overwrites the AW/outv region)
    mfma_nt<0, 0, 0><<<dim3(340, 1, 4), 256, 0, stream>>>(
        PV, nullptr, 256, (long)NI_ * 256,
        UT, nullptr, 256, 65536,
        outv, 256, (long)NI_ * 256,
        8, 1, nullptr, 0, ovp_b, nullptr, nullptr, 0);

    // 10: out_l = G2 @ W2^T + bias2
    k_g2t<<<dim3(1024), 256, 0, stream>>>(G, G2);
    gemm_nt<<<dim3(12, 1, 4), 256, 0, stream>>>(G2, 1024, 0, 65536, W2, 1024, 0, 0,
                                                outl, 768, 0, 49152, 1024, 1.f, nullptr, 0, B2);
}

// Round 7
// 962.216 us; speedup vs baseline: 3.0904x; 1.3593x over previous
//
#include <hip/hip_runtime.h>

#define LB __launch_bounds__(256)

typedef __attribute__((ext_vector_type(8))) short bf16x8;
typedef __attribute__((ext_vector_type(4))) float f32x4;
typedef unsigned int  u32;
typedef unsigned short u16;

// problem sizes
static constexpr int  HT_ = 256, NI_ = 21760;
static constexpr long OUTV_N = 22282240L;   // 4*21760*256
static constexpr float SC_ = 0.0625f;       // HEAD_DIM^-0.5

// workspace offsets (in floats).
static constexpr long WS_KF  = 0;        // K projection      [256][1024]
static constexpr long WS_VL  = 262144;   // val_l projection  [256][1024]
static constexpr long WS_CM  = 524288;   // Cmat f32          [4][256][256]
static constexpr long WS_CB  = 786432;   // cbias             [4][256]
static constexpr long WS_UU  = 787456;   // U f32             [4][256][256]
static constexpr long WS_W2  = 1049600;  // W2                [768][1024]
static constexpr long WS_B2  = 1836032;  // bias2             [768]
static constexpr long WS_WT  = 1836800;  // conv w transposed [64*9][64]
static constexpr long WS_CMX = 1873664;  // col max           [1024]
static constexpr long WS_CSM = 1874688;  // col sum           [1024]
static constexpr long WS_G   = 1875712;  // G = p_l @ v       [4][256][256]
static constexpr long WS_G2  = 2137856;  // G transposed      [4][64][1024]
static constexpr long WS_UT  = 2400000;  // U^T bf16          [4][256 o][256 ht]
static constexpr long WS_SH  = 2531072;  // shared region:
                                         //   phase A: LO conv outputs [16][64][5376] f32
                                         //   phase B: VBT bf16 [4][256 c][21760 i]
                                         //   phase C: PV  bf16 [4][21760 i][256 ht]

__device__ __forceinline__ u16 f2bf(float x){
    u32 u = __float_as_uint(x);
    return (u16)((u + 0x7FFFu + ((u >> 16) & 1u)) >> 16);
}
__device__ __forceinline__ float bf2f(u16 h){ return __uint_as_float(((u32)h) << 16); }

__device__ __forceinline__ f32x4 MFMA(bf16x8 a, bf16x8 b, f32x4 c){
    return __builtin_amdgcn_mfma_f32_16x16x32_bf16(a, b, c, 0, 0, 0);
}

// ---------------------------------------------------------------------------
// Generic MFMA NT GEMM: C[M][N] = A[M][K] * B[N][K]^T, block tile 64x256,
// 4 waves (2m x 2n), K staged 32/step.  LDS rows padded to 40 bf16.
// AMODE: 0 = A bf16, 1 = A f32 row-softmax exp(x-max)*inv, 2 = A f32 hi/lo split
// BMODE: 0 = B bf16, 2 = B f32 hi/lo split
// ATOMIC: 0 = store with biases, 1 = atomicAdd
template<int AMODE, int BMODE, int ATOMIC>
__global__ LB void mfma_nt(const u16* __restrict__ Abf, const float* __restrict__ Af,
                           int lda, long aBS,
                           const u16* __restrict__ Bbf, const float* __restrict__ Bf,
                           int ldb, long bBS,
                           float* __restrict__ C, int ldc, long cBS,
                           int nsteps, int zdiv,
                           const float* __restrict__ biasM, long bmBS,
                           const float* __restrict__ biasN,
                           const float* __restrict__ rmax, const float* __restrict__ rsum,
                           long rsBS)
{
    __shared__ u16 As [64 * 40];
    __shared__ u16 As2[(AMODE == 2) ? 64 * 40 : 8];
    __shared__ u16 Bs [256 * 40];
    __shared__ u16 Bs2[(BMODE == 2) ? 256 * 40 : 8];
    __shared__ float s_max[64], s_inv[64];

    const int tid = threadIdx.x;
    const int z = blockIdx.z;
    const int b = z / zdiv, ks = z - b * zdiv;
    const int m0 = blockIdx.x * 64;
    const int n0 = blockIdx.y * 256;
    const long kbase = (long)ks * nsteps * 32;

    const u16*   Ab  = Abf ? Abf + (long)b * aBS : nullptr;
    const float* Afp = Af  ? Af  + (long)b * aBS : nullptr;
    const u16*   Bb  = Bbf ? Bbf + (long)b * bBS : nullptr;
    const float* Bfp = Bf  ? Bf  + (long)b * bBS : nullptr;
    float* Cb = C + (long)b * cBS;
    const float* bM = biasM ? biasM + (long)b * bmBS : nullptr;

    if (AMODE == 1) {
        if (tid < 64) {
            s_max[tid] = rmax[(long)b * rsBS + m0 + tid];
            s_inv[tid] = 1.0f / rsum[(long)b * rsBS + m0 + tid];
        }
    }

    const int lane = tid & 63, wid = tid >> 6;
    const int wm = wid >> 1, wn = wid & 1;
    const int lr = lane & 15, lk = (lane >> 4) * 8;
    f32x4 acc[2][8] = {};

    const int ar = tid >> 2, aseg = tid & 3;

    for (int it = 0; it < nsteps; ++it) {
        const long kk = kbase + (long)it * 32;
        __syncthreads();
        // ---- stage A: 64 rows x 32 elems
        if (AMODE == 0) {
            *(uint4*)&As[ar * 40 + aseg * 8] =
                *(const uint4*)(Ab + (long)(m0 + ar) * lda + kk + aseg * 8);
        } else if (AMODE == 2) {
            const float4* s = (const float4*)(Afp + (long)(m0 + ar) * lda + kk + aseg * 8);
            float4 x0 = s[0], x1 = s[1];
            float xs[8] = {x0.x, x0.y, x0.z, x0.w, x1.x, x1.y, x1.z, x1.w};
            u32 hw[4], lw[4];
            #pragma unroll
            for (int p = 0; p < 4; ++p) {
                u16 h0 = f2bf(xs[2*p]),   h1 = f2bf(xs[2*p+1]);
                u16 l0 = f2bf(xs[2*p]   - bf2f(h0));
                u16 l1 = f2bf(xs[2*p+1] - bf2f(h1));
                hw[p] = (u32)h0 | ((u32)h1 << 16);
                lw[p] = (u32)l0 | ((u32)l1 << 16);
            }
            uint4 th; th.x = hw[0]; th.y = hw[1]; th.z = hw[2]; th.w = hw[3];
            uint4 tl; tl.x = lw[0]; tl.y = lw[1]; tl.z = lw[2]; tl.w = lw[3];
            *(uint4*)&As [ar * 40 + aseg * 8] = th;
            *(uint4*)&As2[ar * 40 + aseg * 8] = tl;
        } else {
            const float4* s = (const float4*)(Afp + (long)(m0 + ar) * lda + kk + aseg * 8);
            float4 x0 = s[0], x1 = s[1];
            float xs[8] = {x0.x, x0.y, x0.z, x0.w, x1.x, x1.y, x1.z, x1.w};
            float mm = s_max[ar], iv = s_inv[ar];
            u32 hw[4];
            #pragma unroll
            for (int p = 0; p < 4; ++p) {
                u16 h0 = f2bf(__expf(xs[2*p]   - mm) * iv);
                u16 h1 = f2bf(__expf(xs[2*p+1] - mm) * iv);
                hw[p] = (u32)h0 | ((u32)h1 << 16);
            }
            uint4 th; th.x = hw[0]; th.y = hw[1]; th.z = hw[2]; th.w = hw[3];
            *(uint4*)&As[ar * 40 + aseg * 8] = th;
        }
        // ---- stage B: 256 rows x 32 elems, row n = tid
        if (BMODE == 0) {
            const uint4* s = (const uint4*)(Bb + (long)(n0 + tid) * ldb + kk);
            uint4* d = (uint4*)&Bs[tid * 40];
            d[0] = s[0]; d[1] = s[1]; d[2] = s[2]; d[3] = s[3];
        } else {
            const float4* s = (const float4*)(Bfp + (long)(n0 + tid) * ldb + kk);
            float xs[32];
            #pragma unroll
            for (int q = 0; q < 8; ++q) {
                float4 t = s[q];
                xs[4*q] = t.x; xs[4*q+1] = t.y; xs[4*q+2] = t.z; xs[4*q+3] = t.w;
            }
            u32 hw[16], lw[16];
            #pragma unroll
            for (int p = 0; p < 16; ++p) {
                u16 h0 = f2bf(xs[2*p]),   h1 = f2bf(xs[2*p+1]);
                u16 l0 = f2bf(xs[2*p]   - bf2f(h0));
                u16 l1 = f2bf(xs[2*p+1] - bf2f(h1));
                hw[p] = (u32)h0 | ((u32)h1 << 16);
                lw[p] = (u32)l0 | ((u32)l1 << 16);
            }
            uint4* dh = (uint4*)&Bs [tid * 40];
            uint4* dl = (uint4*)&Bs2[tid * 40];
            #pragma unroll
            for (int g = 0; g < 4; ++g) {
                uint4 t; t.x = hw[4*g]; t.y = hw[4*g+1]; t.z = hw[4*g+2]; t.w = hw[4*g+3];
                dh[g] = t;
                uint4 t2; t2.x = lw[4*g]; t2.y = lw[4*g+1]; t2.z = lw[4*g+2]; t2.w = lw[4*g+3];
                dl[g] = t2;
            }
        }
        __syncthreads();
        // ---- compute
        bf16x8 a0 = *(const bf16x8*)&As[(wm * 32 + lr) * 40 + lk];
        bf16x8 a1 = *(const bf16x8*)&As[(wm * 32 + 16 + lr) * 40 + lk];
        bf16x8 a0l, a1l;
        if (AMODE == 2) {
            a0l = *(const bf16x8*)&As2[(wm * 32 + lr) * 40 + lk];
            a1l = *(const bf16x8*)&As2[(wm * 32 + 16 + lr) * 40 + lk];
        }
        #pragma unroll
        for (int nt = 0; nt < 8; ++nt) {
            const int boff = (wn * 128 + nt * 16 + lr) * 40 + lk;
            bf16x8 bh = *(const bf16x8*)&Bs[boff];
            acc[0][nt] = MFMA(a0, bh, acc[0][nt]);
            acc[1][nt] = MFMA(a1, bh, acc[1][nt]);
            if (AMODE == 2 && BMODE == 2) {
                bf16x8 bl = *(const bf16x8*)&Bs2[boff];
                acc[0][nt] = MFMA(a0,  bl, acc[0][nt]);
                acc[0][nt] = MFMA(a0l, bh, acc[0][nt]);
                acc[1][nt] = MFMA(a1,  bl, acc[1][nt]);
                acc[1][nt] = MFMA(a1l, bh, acc[1][nt]);
            }
        }
    }
    // ---- epilogue.  D: col = lane&15, row = (lane>>4)*4 + reg
    const int cr = (lane >> 4) * 4;
    #pragma unroll
    for (int mt = 0; mt < 2; ++mt) {
        #pragma unroll
        for (int nt = 0; nt < 8; ++nt) {
            f32x4 a = acc[mt][nt];
            const long gm0 = m0 + wm * 32 + mt * 16 + cr;
            const int  gn  = n0 + wn * 128 + nt * 16 + lr;
            float bn = (!ATOMIC && biasN) ? biasN[gn] : 0.f;
            #pragma unroll
            for (int rr = 0; rr < 4; ++rr) {
                if (ATOMIC) {
                    atomicAdd(Cb + (gm0 + rr) * (long)ldc + gn, a[rr]);
                } else {
                    float bm = bM ? bM[gm0 + rr] : 0.f;
                    Cb[(gm0 + rr) * (long)ldc + gn] = a[rr] + bm + bn;
                }
            }
        }
    }
}

// ---------------------------------------------------------------------------
// f32 split-K NT GEMM with atomic accumulation.  C must be pre-zeroed.
// z = ((b * nproj + p) * ksplit + ks).  ks==0 block folds biasN in.
__global__ LB void gemm_nt_sk(const float* __restrict__ A, int lda, long aZb,
                              const float* __restrict__ B0, const float* __restrict__ B1,
                              int ldb,
                              float* __restrict__ C0, float* __restrict__ C1,
                              int ldc, long cZb,
                              int kslice, int ksplit, int nproj,
                              const float* __restrict__ bN0, const float* __restrict__ bN1,
                              float scale)
{
    int z = blockIdx.z;
    const int ks = z % ksplit; z /= ksplit;
    const int p  = z % nproj;  z /= nproj;
    const int b  = z;
    const float* Bm = p ? B1 : B0;
    const float* bN = p ? bN1 : bN0;
    float* C = (p ? C1 : C0) + (long)b * cZb;
    const float* Ab = A + (long)b * aZb;
    const int m0 = blockIdx.y * 64, n0 = blockIdx.x * 64;
    const int k0 = ks * kslice;
    __shared__ float As[64][36];
    __shared__ float Bs[64][36];
    const int tid = threadIdx.x;
    const int tm = (tid >> 4) * 4, tn = tid & 15;
    float acc[4][4] = {};
    for (int kb = 0; kb < kslice; kb += 32) {
        __syncthreads();
        #pragma unroll
        for (int idx = tid; idx < 2048; idx += 256) {
            int r = idx >> 5, c = idx & 31;
            As[r][c] = Ab[(long)(m0 + r) * lda + k0 + kb + c];
            Bs[r][c] = Bm[(long)(n0 + r) * ldb + k0 + kb + c];
        }
        __syncthreads();
        #pragma unroll
        for (int kk = 0; kk < 32; kk += 4) {
            float4 a0 = *(const float4*)&As[tm + 0][kk];
            float4 a1 = *(const float4*)&As[tm + 1][kk];
            float4 a2 = *(const float4*)&As[tm + 2][kk];
            float4 a3 = *(const float4*)&As[tm + 3][kk];
            float4 b0 = *(const float4*)&Bs[tn +  0][kk];
            float4 b1 = *(const float4*)&Bs[tn + 16][kk];
            float4 b2 = *(const float4*)&Bs[tn + 32][kk];
            float4 b3 = *(const float4*)&Bs[tn + 48][kk];
#define NT_ROW(m, av) \
            acc[m][0] += av.x*b0.x + av.y*b0.y + av.z*b0.z + av.w*b0.w; \
            acc[m][1] += av.x*b1.x + av.y*b1.y + av.z*b1.z + av.w*b1.w; \
            acc[m][2] += av.x*b2.x + av.y*b2.y + av.z*b2.z + av.w*b2.w; \
            acc[m][3] += av.x*b3.x + av.y*b3.y + av.z*b3.z + av.w*b3.w;
            NT_ROW(0, a0) NT_ROW(1, a1) NT_ROW(2, a2) NT_ROW(3, a3)
#undef NT_ROW
        }
    }
    #pragma unroll
    for (int im = 0; im < 4; ++im) {
        #pragma unroll
        for (int q = 0; q < 4; ++q) {
            float vadd = scale * acc[im][q];
            if (ks == 0 && bN) vadd += bN[n0 + tn + 16*q];
            atomicAdd(&C[(long)(m0 + tm + im) * ldc + n0 + tn + 16*q], vadd);
        }
    }
}

// f32 64x64-tile GEMM, NT (bank-conflict-fixed lane map) — per-head folded mats
__global__ LB void gemm_nt(const float* __restrict__ A, int lda, long aZb, long aZh,
                           const float* __restrict__ Bm, int ldb, long bZb, long bZh,
                           float* __restrict__ C, int ldo, long oZb, long oZh,
                           int K, float scale,
                           const float* __restrict__ biasM, long bmZh,
                           const float* __restrict__ biasN)
{
    const int z = blockIdx.z, zb = z >> 2, zh = z & 3;
    A  += (long)zb * aZb + (long)zh * aZh;
    Bm += (long)zb * bZb + (long)zh * bZh;
    C  += (long)zb * oZb + (long)zh * oZh;
    if (biasM) biasM += (long)zh * bmZh;
    const int m0 = blockIdx.y * 64, n0 = blockIdx.x * 64;
    __shared__ float As[64][36];
    __shared__ float Bs[64][36];
    const int tid = threadIdx.x;
    const int tm = (tid >> 4) * 4, tn = tid & 15;
    float acc[4][4] = {};
    for (int kb = 0; kb < K; kb += 32) {
        __syncthreads();
        #pragma unroll
        for (int idx = tid; idx < 2048; idx += 256) {
            int r = idx >> 5, c = idx & 31;
            As[r][c] = A[(long)(m0 + r) * lda + kb + c];
            Bs[r][c] = Bm[(long)(n0 + r) * ldb + kb + c];
        }
        __syncthreads();
        #pragma unroll
        for (int kk = 0; kk < 32; kk += 4) {
            float4 a0 = *(const float4*)&As[tm + 0][kk];
            float4 a1 = *(const float4*)&As[tm + 1][kk];
            float4 a2 = *(const float4*)&As[tm + 2][kk];
            float4 a3 = *(const float4*)&As[tm + 3][kk];
            float4 b0 = *(const float4*)&Bs[tn +  0][kk];
            float4 b1 = *(const float4*)&Bs[tn + 16][kk];
            float4 b2 = *(const float4*)&Bs[tn + 32][kk];
            float4 b3 = *(const float4*)&Bs[tn + 48][kk];
#define NT_ROW(m, av) \
            acc[m][0] += av.x*b0.x + av.y*b0.y + av.z*b0.z + av.w*b0.w; \
            acc[m][1] += av.x*b1.x + av.y*b1.y + av.z*b1.z + av.w*b1.w; \
            acc[m][2] += av.x*b2.x + av.y*b2.y + av.z*b2.z + av.w*b2.w; \
            acc[m][3] += av.x*b3.x + av.y*b3.y + av.z*b3.z + av.w*b3.w;
            NT_ROW(0, a0) NT_ROW(1, a1) NT_ROW(2, a2) NT_ROW(3, a3)
#undef NT_ROW
        }
    }
    #pragma unroll
    for (int im = 0; im < 4; ++im) {
        float bm = biasM ? biasM[m0 + tm + im] : 0.f;
        #pragma unroll
        for (int q = 0; q < 4; ++q) {
            float bn = biasN ? biasN[n0 + tn + 16*q] : 0.f;
            C[(long)(m0 + tm + im) * ldo + n0 + tn + 16*q] = scale * acc[im][q] + bm + bn;
        }
    }
}

// f32 64x64-tile GEMM, NN
__global__ LB void gemm_nn(const float* __restrict__ A, int lda, long aZb, long aZh,
                           const float* __restrict__ Bm, int ldb, long bZb, long bZh,
                           float* __restrict__ C, int ldo, long oZb, long oZh,
                           int K, float scale)
{
    const int z = blockIdx.z, zb = z >> 2, zh = z & 3;
    A  += (long)zb * aZb + (long)zh * aZh;
    Bm += (long)zb * bZb + (long)zh * bZh;
    C  += (long)zb * oZb + (long)zh * oZh;
    const int m0 = blockIdx.y * 64, n0 = blockIdx.x * 64;
    __shared__ float As[64][36];
    __shared__ float Bs[32][68];
    const int tid = threadIdx.x;
    const int tm = (tid >> 4) * 4, tn = (tid & 15) * 4;
    float acc[4][4] = {};
    for (int kb = 0; kb < K; kb += 32) {
        __syncthreads();
        #pragma unroll
        for (int idx = tid; idx < 2048; idx += 256) {
            int r = idx >> 5, c = idx & 31;
            As[r][c] = A[(long)(m0 + r) * lda + kb + c];
            int r2 = idx >> 6, c2 = idx & 63;
            Bs[r2][c2] = Bm[(long)(kb + r2) * ldb + n0 + c2];
        }
        __syncthreads();
        #pragma unroll
        for (int kk = 0; kk < 32; kk += 4) {
            float4 a0 = *(const float4*)&As[tm + 0][kk];
            float4 a1 = *(const float4*)&As[tm + 1][kk];
            float4 a2 = *(const float4*)&As[tm + 2][kk];
            float4 a3 = *(const float4*)&As[tm + 3][kk];
            float4 b0 = *(const float4*)&Bs[kk + 0][tn];
            float4 b1 = *(const float4*)&Bs[kk + 1][tn];
            float4 b2 = *(const float4*)&Bs[kk + 2][tn];
            float4 b3 = *(const float4*)&Bs[kk + 3][tn];
#define NN_ROW(m, av) \
            acc[m][0] += av.x*b0.x + av.y*b1.x + av.z*b2.x + av.w*b3.x; \
            acc[m][1] += av.x*b0.y + av.y*b1.y + av.z*b2.y + av.w*b3.y; \
            acc[m][2] += av.x*b0.z + av.y*b1.z + av.z*b2.z + av.w*b3.z; \
            acc[m][3] += av.x*b0.w + av.y*b1.w + av.z*b2.w + av.w*b3.w;
            NN_ROW(0, a0) NN_ROW(1, a1) NN_ROW(2, a2) NN_ROW(3, a3)
#undef NN_ROW
        }
    }
    #pragma unroll
    for (int im = 0; im < 4; ++im) {
        float4 r;
        r.x = scale * acc[im][0];
        r.y = scale * acc[im][1];
        r.z = scale * acc[im][2];
        r.w = scale * acc[im][3];
        *(float4*)&C[(long)(m0 + tm + im) * ldo + n0 + tn] = r;
    }
}

// cbias[b][ht] = SCALE * sum_d vp_b[h*256+d] * KF[(b*64+t)*1024 + h*256+d]
__global__ LB void k_cbias(const float* __restrict__ KF, const float* __restrict__ vp_b,
                           float* __restrict__ cb)
{
    int idx = blockIdx.x * 256 + threadIdx.x;      // 0..1023
    int b = idx >> 8, ht = idx & 255, h = ht >> 6, t = ht & 63;
    const float* kr = KF + (long)(b * 64 + t) * 1024 + h * 256;
    const float* br = vp_b + h * 256;
    float s = 0.f;
    for (int d = 0; d < 256; d += 4) {
        float4 a = *(const float4*)&kr[d];
        float4 c = *(const float4*)&br[d];
        s += a.x*c.x + a.y*c.y + a.z*c.z + a.w*c.w;
    }
    cb[idx] = s * SC_;
}

// bias2[o] = olp_b[o] + sum_hd olp_w[o*1024+hd]*vvp_b[hd]
__global__ LB void k_bias2(const float* __restrict__ olp_w, const float* __restrict__ olp_b,
                           const float* __restrict__ vvp_b, float* __restrict__ b2)
{
    int o = blockIdx.x * 256 + threadIdx.x;        // 0..767
    const float* wr = olp_w + (long)o * 1024;
    float s = olp_b[o];
    for (int k = 0; k < 1024; k += 4) {
        float4 a = *(const float4*)&wr[k];
        float4 c = *(const float4*)&vvp_b[k];
        s += a.x*c.x + a.y*c.y + a.z*c.z + a.w*c.w;
    }
    b2[o] = s;
}

// transpose conv weights: Wt[(ti*9+tap)*64 + to] = down_w[((to*64+ti)*9 + tap)]
__global__ LB void k_wt(const float* __restrict__ dw, float* __restrict__ Wt)
{
    int idx = blockIdx.x * 256 + threadIdx.x;      // < 36864
    int to = idx / 576, rem = idx - to * 576;
    int ti = rem / 9, tap = rem - ti * 9;
    Wt[(ti * 9 + tap) * 64 + to] = dw[idx];
}

// stride-2 3x3 conv, 64ch->64ch (inputs are ORIGINAL aw levels 0..2)
__global__ LB void k_conv(const float* __restrict__ aw, const float* __restrict__ Wt,
                          const float* __restrict__ down_b, float* __restrict__ lo)
{
    __shared__ float ins[16][17][36];
    const int bx = blockIdx.x, bh = blockIdx.y;
    int w_out, w_in, in_off, lo_off, ty, tx;
    if (bx < 32)      { w_out = 64; w_in = 128; in_off = 0;     lo_off = 0;    ty = bx >> 2;       tx = bx & 3; }
    else if (bx < 40) { w_out = 32; w_in = 64;  in_off = 16384; lo_off = 4096; int e = bx - 32; ty = e >> 1; tx = e & 1; }
    else              { w_out = 16; w_in = 32;  in_off = 20480; lo_off = 5120; ty = bx - 40;       tx = 0; }
    const int y0 = ty * 8, x0 = tx * 16;
    const int tid = threadIdx.x;
    const int to0 = (tid & 15) * 4;
    const int pg = tid >> 4;
    const int py = pg & 7;
    const int xbase = (pg >> 3) * 8;
    const float* in_base = aw + (long)(bh >> 2) * HT_ * NI_ + (long)((bh & 3) * 64) * NI_ + in_off;
    float acc[4][8] = {};
    for (int tc = 0; tc < 64; tc += 16) {
        __syncthreads();
        for (int idx = tid; idx < 16 * 561; idx += 256) {
            int ti = idx / 561, rem = idx - ti * 561;
            int r = rem / 33, c = rem - r * 33;
            int gy = 2 * y0 - 1 + r, gx = 2 * x0 - 1 + c;
            float vv = 0.f;
            if (gy >= 0 && gy < w_in && gx >= 0 && gx < w_in)
                vv = in_base[(long)(tc + ti) * NI_ + gy * w_in + gx];
            ins[ti][r][c] = vv;
        }
        __syncthreads();
        for (int ti = 0; ti < 16; ++ti) {
            const int tig = tc + ti;
            #pragma unroll
            for (int ky = 0; ky < 3; ++ky) {
                const int r = 2 * py + ky;
                const float* rowp = &ins[ti][r][2 * xbase];
                float rv[20];
                #pragma unroll
                for (int q = 0; q < 5; ++q) {
                    float4 f = *(const float4*)(rowp + 4 * q);
                    rv[4*q+0] = f.x; rv[4*q+1] = f.y; rv[4*q+2] = f.z; rv[4*q+3] = f.w;
                }
                #pragma unroll
                for (int kx = 0; kx < 3; ++kx) {
                    float4 w4 = *(const float4*)&Wt[(tig * 9 + ky * 3 + kx) * 64 + to0];
                    #pragma unroll
                    for (int x = 0; x < 8; ++x) {
                        float iv = rv[2 * x + kx];
                        acc[0][x] += iv * w4.x;
                        acc[1][x] += iv * w4.y;
                        acc[2][x] += iv * w4.z;
                        acc[3][x] += iv * w4.w;
                    }
                }
            }
        }
    }
    const long lo_base = (long)bh * 64 * 5376;
    #pragma unroll
    for (int j = 0; j < 4; ++j) {
        float bias = down_b[to0 + j];
        float* op = lo + lo_base + (long)(to0 + j) * 5376 + lo_off + (y0 + py) * w_out + x0 + xbase;
        #pragma unroll
        for (int x = 0; x < 8; ++x) op[x] = acc[j][x] + bias;
    }
}

// in-place pyramid update for one level (launched lvl 0,1,2,3 in order)
__global__ LB void k_update(float* __restrict__ aw, const float* __restrict__ lo,
                            const float* __restrict__ simp, int lvl, int w_out, int off_out,
                            int w_src, int off_src, int lo_off)
{
    const int bht = blockIdx.y;
    const int pix = blockIdx.x * 256 + threadIdx.x;
    float* base = aw + (long)bht * NI_;
    float cur = base[off_out + pix];
    float alpha = simp[0];
    float upd = 0.f;
    if (lvl < 3) {
        int y = pix / w_out, x = pix - y * w_out;
        int j0 = (y - 1) >> 1; float wy = (y & 1) ? 0.25f : 0.75f;
        int i0 = (x - 1) >> 1; float wx = (x & 1) ? 0.25f : 0.75f;
        int j0c = j0 < 0 ? 0 : j0, j1c = j0 + 1 < w_src ? j0 + 1 : w_src - 1;
        int i0c = i0 < 0 ? 0 : i0, i1c = i0 + 1 < w_src ? i0 + 1 : w_src - 1;
        const float* src = base + off_src;
        float v00 = src[j0c * w_src + i0c], v01 = src[j0c * w_src + i1c];
        float v10 = src[j1c * w_src + i0c], v11 = src[j1c * w_src + i1c];
        float up = (1.f - wy) * ((1.f - wx) * v00 + wx * v01) + wy * ((1.f - wx) * v10 + wx * v11);
        upd += alpha * (up - cur);
    }
    if (lvl > 0) {
        float lov = lo[(long)bht * 5376 + lo_off + pix];
        upd += alpha * (lov - cur);
    }
    base[off_out + pix] = cur + 0.5f * upd;
}

// per-(b,ht) row max and sumexp over 21760 image positions (for p_l)
__global__ LB void k_colstats(const float* __restrict__ aw, float* __restrict__ cmax,
                              float* __restrict__ csum)
{
    const int bht = blockIdx.x;
    const float* row = aw + (long)bht * NI_;
    const int tid = threadIdx.x;
    float m = -3.0e38f, s = 0.f;
    for (int i = tid; i < NI_; i += 256) {
        float vv = row[i];
        if (vv > m) { s *= __expf(m - vv); m = vv; }
        s += __expf(vv - m);
    }
    for (int off = 32; off > 0; off >>= 1) {
        float om = __shfl_down(m, off, 64);
        float os = __shfl_down(s, off, 64);
        float M = fmaxf(m, om);
        s = s * __expf(m - M) + os * __expf(om - M);
        m = M;
    }
    __shared__ float sm[4], ss[4];
    int wave = tid >> 6;
    if ((tid & 63) == 0) { sm[wave] = m; ss[wave] = s; }
    __syncthreads();
    if (tid == 0) {
        m = sm[0]; s = ss[0];
        for (int w = 1; w < 4; ++w) {
            float M = fmaxf(m, sm[w]);
            s = s * __expf(m - M) + ss[w] * __expf(sm[w] - M);
            m = M;
        }
        cmax[bht] = m; csum[bht] = s;
    }
}

// v[b][i][c] f32 -> VBT[b][c][i] bf16  (64x64 LDS tile transpose)
__global__ LB void k_cvt_vt(const float* __restrict__ v, u16* __restrict__ VBT)
{
    const int b = blockIdx.z, i0 = blockIdx.x * 64, c0 = blockIdx.y * 64;
    __shared__ u16 Ts[64][72];
    const int tid = threadIdx.x;
    const int r = tid >> 2, seg = tid & 3;
    const float4* s = (const float4*)(v + ((long)b * NI_ + i0 + r) * 256 + c0 + seg * 16);
    #pragma unroll
    for (int q = 0; q < 4; ++q) {
        float4 x = s[q];
        Ts[r][seg * 16 + 4*q + 0] = f2bf(x.x);
        Ts[r][seg * 16 + 4*q + 1] = f2bf(x.y);
        Ts[r][seg * 16 + 4*q + 2] = f2bf(x.z);
        Ts[r][seg * 16 + 4*q + 3] = f2bf(x.w);
    }
    __syncthreads();
    const int cr = tid >> 2, is = tid & 3;
    u32 o[8];
    #pragma unroll
    for (int j = 0; j < 8; ++j)
        o[j] = (u32)Ts[is * 16 + 2*j][cr] | ((u32)Ts[is * 16 + 2*j + 1][cr] << 16);
    uint4* d = (uint4*)(VBT + ((long)b * 256 + c0 + cr) * NI_ + i0 + is * 16);
    uint4 t0; t0.x = o[0]; t0.y = o[1]; t0.z = o[2]; t0.w = o[3];
    uint4 t1; t1.x = o[4]; t1.y = o[5]; t1.z = o[6]; t1.w = o[7];
    d[0] = t0; d[1] = t1;
}

// U[b][ht][o] f32 -> UT[b][o][ht] bf16
__global__ LB void k_t_u(const float* __restrict__ U, u16* __restrict__ UT)
{
    const int b = blockIdx.z, r0 = blockIdx.x * 64, c0 = blockIdx.y * 64;
    __shared__ float Fs[64][68];
    const int tid = threadIdx.x;
    const int r = tid >> 2, seg = tid & 3;
    const float4* s = (const float4*)(U + ((long)b * 256 + r0 + r) * 256 + c0 + seg * 16);
    #pragma unroll
    for (int q = 0; q < 4; ++q) *(float4*)&Fs[r][seg * 16 + 4*q] = s[q];
    __syncthreads();
    const int cr = tid >> 2, is = tid & 3;
    u32 o[8];
    #pragma unroll
    for (int j = 0; j < 8; ++j)
        o[j] = (u32)f2bf(Fs[is * 16 + 2*j][cr]) | ((u32)f2bf(Fs[is * 16 + 2*j + 1][cr]) << 16);
    uint4* d = (uint4*)(UT + ((long)b * 256 + c0 + cr) * 256 + r0 + is * 16);
    uint4 t0; t0.x = o[0]; t0.y = o[1]; t0.z = o[2]; t0.w = o[3];
    uint4 t1; t1.x = o[4]; t1.y = o[5]; t1.z = o[6]; t1.w = o[7];
    d[0] = t0; d[1] = t1;
}

// PV[b][i][ht] bf16 = softmax over t (within head) of AW[b][ht][i].  i-tile = 32.
__global__ LB void k_pv(const float* __restrict__ aw, u16* __restrict__ PV)
{
    const int b = blockIdx.y;
    const int i0 = blockIdx.x * 32;
    const int tid = threadIdx.x;
    __shared__ float tile[256][36];
    const float* awb = aw + (long)b * HT_ * NI_;
    const float4* src = (const float4*)(awb + (long)tid * NI_ + i0);
    #pragma unroll
    for (int q = 0; q < 8; ++q) *(float4*)&tile[tid][q * 4] = src[q];
    __syncthreads();
    if (tid < 128) {
        int h = tid >> 5, i = tid & 31;
        float m = -3.0e38f;
        for (int t = 0; t < 64; ++t) m = fmaxf(m, tile[h * 64 + t][i]);
        float s = 0.f;
        for (int t = 0; t < 64; ++t) s += __expf(tile[h * 64 + t][i] - m);
        float inv = 1.f / s;
        u32* dst = (u32*)(PV + ((long)b * NI_ + i0 + i) * 256 + h * 64);
        #pragma unroll 4
        for (int t = 0; t < 32; ++t) {
            u16 p0 = f2bf(__expf(tile[h * 64 + 2*t][i]     - m) * inv);
            u16 p1 = f2bf(__expf(tile[h * 64 + 2*t + 1][i] - m) * inv);
            dst[t] = (u32)p0 | ((u32)p1 << 16);
        }
    }
}

// G2[b][t][h*256+c] = G[b][h*64+t][c]
__global__ LB void k_g2t(const float* __restrict__ G, float* __restrict__ G2)
{
    int idx = blockIdx.x * 256 + threadIdx.x;   // < 262144
    int b = idx >> 16, r = idx & 65535;
    int t = r >> 10, e = r & 1023;
    int h = e >> 8, c = e & 255;
    G2[idx] = G[(long)b * 65536 + (h * 64 + t) * 256 + c];
}

// ---------------------------------------------------------------------------
extern "C" void kernel_launch(void* const* d_in, const int* in_sizes, int n_in,
                              void* d_out, int out_size, void* d_ws, size_t ws_size,
                              hipStream_t stream)
{
    const float* v      = (const float*)d_in[0];
    const float* l      = (const float*)d_in[1];
    const float* simp   = (const float*)d_in[2];
    const float* vp_w   = (const float*)d_in[3];
    const float* vp_b   = (const float*)d_in[4];
    const float* lp_w   = (const float*)d_in[5];
    const float* lp_b   = (const float*)d_in[6];
    const float* vvp_w  = (const float*)d_in[7];
    const float* vvp_b  = (const float*)d_in[8];
    const float* vlp_w  = (const float*)d_in[9];
    const float* vlp_b  = (const float*)d_in[10];
    const float* ovp_w  = (const float*)d_in[11];
    const float* ovp_b  = (const float*)d_in[12];
    const float* olp_w  = (const float*)d_in[13];
    const float* olp_b  = (const float*)d_in[14];
    const float* down_w = (const float*)d_in[15];
    const float* down_b = (const float*)d_in[16];

    float* outv = (float*)d_out;
    float* outl = outv + OUTV_N;
    float* AW   = outv;                 // AW lives in the outv region (dead before attnv writes)
    float* ws = (float*)d_ws;
    float* KF  = ws + WS_KF;
    float* VL  = ws + WS_VL;
    float* CM  = ws + WS_CM;
    float* CB  = ws + WS_CB;
    float* UU  = ws + WS_UU;
    float* W2  = ws + WS_W2;
    float* B2  = ws + WS_B2;
    float* WT  = ws + WS_WT;
    float* CMX = ws + WS_CMX;
    float* CSM = ws + WS_CSM;
    float* G   = ws + WS_G;
    float* G2  = ws + WS_G2;
    u16*   UT  = (u16*)(ws + WS_UT);
    float* LO  = ws + WS_SH;            // phase A
    u16*   VBT = (u16*)(ws + WS_SH);    // phase B (after updates)
    u16*   PV  = (u16*)(ws + WS_SH);    // phase C (after plv)

    // 0: zero split-K accumulation targets (KF+VL contiguous; outl; G)
    hipMemsetAsync(KF, 0, 524288 * sizeof(float), stream);
    hipMemsetAsync(outl, 0, 196608 * sizeof(float), stream);
    hipMemsetAsync(G, 0, 262144 * sizeof(float), stream);

    // 1: projections KF = l@lp_w.T+lp_b, VL = l@vlp_w.T+vlp_b  (fused, split-K x3)
    gemm_nt_sk<<<dim3(16, 4, 6), 256, 0, stream>>>(l, 768, 0, lp_w, vlp_w, 768,
                                                   KF, VL, 1024, 0,
                                                   256, 3, 2, lp_b, vlp_b, 1.f);
    // 2: small folded mats
    gemm_nn<<<dim3(4, 1, 16), 256, 0, stream>>>(KF, 1024, 65536, 256, vp_w, 256, 0, 65536,
                                                CM, 256, 65536, 16384, 256, SC_);
    k_cbias<<<dim3(4), 256, 0, stream>>>(KF, vp_b, CB);
    gemm_nt<<<dim3(4, 1, 16), 256, 0, stream>>>(VL, 1024, 65536, 256, ovp_w, 1024, 0, 256,
                                                UU, 256, 65536, 16384, 256, 1.f, nullptr, 0, nullptr);
    gemm_nn<<<dim3(4, 12, 4), 256, 0, stream>>>(olp_w, 1024, 0, 256, vvp_w, 256, 0, 65536,
                                                W2, 1024, 0, 256, 256, 1.f);
    k_bias2<<<dim3(3), 256, 0, stream>>>(olp_w, olp_b, vvp_b, B2);
    k_t_u<<<dim3(4, 4, 4), 256, 0, stream>>>(UU, UT);

    // 3: AW = CM @ v^T + cbias  (bf16x3 split MFMA; M=256, N=21760, K=256)
    mfma_nt<2, 2, 0><<<dim3(4, 85, 4), 256, 0, stream>>>(
        nullptr, CM, 256, 65536,
        nullptr, v, 256, (long)NI_ * 256,
        AW, NI_, (long)HT_ * NI_,
        8, 1, CB, 256, nullptr, nullptr, nullptr, 0);

    // 4: conv downsample + in-place pyramid update
    k_wt<<<dim3(144), 256, 0, stream>>>(down_w, WT);
    k_conv<<<dim3(42, 16), 256, 0, stream>>>(AW, WT, down_b, LO);
    k_update<<<dim3(64, 1024), 256, 0, stream>>>(AW, LO, simp, 0, 128, 0,     64, 16384, 0);
    k_update<<<dim3(16, 1024), 256, 0, stream>>>(AW, LO, simp, 1, 64, 16384,  32, 20480, 0);
    k_update<<<dim3(4, 1024), 256, 0, stream>>>(AW, LO, simp, 2, 32, 20480,  16, 21504, 4096);
    k_update<<<dim3(1, 1024), 256, 0, stream>>>(AW, LO, simp, 3, 16, 21504,   0, 0,     5120);

    // 5: column-softmax stats over i per (b,ht)
    k_colstats<<<dim3(1024), 256, 0, stream>>>(AW, CMX, CSM);

    // 6: v^T bf16 (overwrites LO region — LO is dead)
    k_cvt_vt<<<dim3(340, 4, 4), 256, 0, stream>>>(v, VBT);

    // 7: G = p_l @ v   (softmax-in-staging MFMA, split-K x17 with atomics)
    mfma_nt<1, 0, 1><<<dim3(4, 1, 68), 256, 0, stream>>>(
        nullptr, AW, NI_, (long)HT_ * NI_,
        VBT, nullptr, NI_, (long)256 * NI_,
        G, 256, 65536,
        40, 17, nullptr, 0, nullptr, CMX, CSM, 256);

    // 8: PV bf16 (overwrites VBT region — VBT is dead)
    k_pv<<<dim3(680, 4), 256, 0, stream>>>(AW, PV);

    // 9: out_v = PV @ UT^T + ovp_b  (MFMA; overwrites the AW/outv region)
    mfma_nt<0, 0, 0><<<dim3(340, 1, 4), 256, 0, stream>>>(
        PV, nullptr, 256, (long)NI_ * 256,
        UT, nullptr, 256, 65536,
        outv, 256, (long)NI_ * 256,
        8, 1, nullptr, 0, ovp_b, nullptr, nullptr, 0);

    // 10: out_l = G2 @ W2^T + bias2  (split-K x4 atomic)
    k_g2t<<<dim3(1024), 256, 0, stream>>>(G, G2);
    gemm_nt_sk<<<dim3(12, 1, 16), 256, 0, stream>>>(G2, 1024, 65536, W2, nullptr, 1024,
                                                    outl, nullptr, 768, 49152,
                                                    256, 4, 1, B2, nullptr, 1.f);
}

// Round 8
// 917.081 us; speedup vs baseline: 3.2425x; 1.0492x over previous
//
#include <hip/hip_runtime.h>

#define LB __launch_bounds__(256)

typedef __attribute__((ext_vector_type(8))) short bf16x8;
typedef __attribute__((ext_vector_type(4))) float f32x4;
typedef unsigned int  u32;
typedef unsigned short u16;

// problem sizes
static constexpr int  HT_ = 256, NI_ = 21760;
static constexpr long OUTV_N = 22282240L;   // 4*21760*256
static constexpr float SC_ = 0.0625f;       // HEAD_DIM^-0.5

// workspace offsets (in floats).
static constexpr long WS_KF  = 0;        // K projection      [256][1024]
static constexpr long WS_VL  = 262144;   // val_l projection  [256][1024]
static constexpr long WS_CM  = 524288;   // Cmat f32          [4][256][256]
static constexpr long WS_CB  = 786432;   // cbias             [4][256]
static constexpr long WS_UU  = 787456;   // U f32             [4][256][256]
static constexpr long WS_W2  = 1049600;  // W2                [768][1024]
static constexpr long WS_B2  = 1836032;  // bias2             [768]
static constexpr long WS_WT  = 1836800;  // conv w transposed [64*9][64]
static constexpr long WS_CMX = 1873664;  // col max           [1024]
static constexpr long WS_CSM = 1874688;  // col sum           [1024]
static constexpr long WS_G   = 1875712;  // G = p_l @ v       [4][256][256]
static constexpr long WS_G2  = 2137856;  // G transposed      [4][64][1024]
static constexpr long WS_UT  = 2400000;  // U^T bf16          [4][256 o][256 ht]
static constexpr long WS_SH  = 2531072;  // shared region:
                                         //   phase A: LO conv outputs [16][64][5376] f32
                                         //   phase B: VBT bf16 [4][256 c][21760 i]
                                         //   phase C: PV  bf16 [4][21760 i][256 ht]

__device__ __forceinline__ u16 f2bf(float x){
    u32 u = __float_as_uint(x);
    return (u16)((u + 0x7FFFu + ((u >> 16) & 1u)) >> 16);
}
__device__ __forceinline__ float bf2f(u16 h){ return __uint_as_float(((u32)h) << 16); }

__device__ __forceinline__ f32x4 MFMA(bf16x8 a, bf16x8 b, f32x4 c){
    return __builtin_amdgcn_mfma_f32_16x16x32_bf16(a, b, c, 0, 0, 0);
}

// ---------------------------------------------------------------------------
// Generic MFMA NT GEMM: C[M][N] = A[M][K] * B[N][K]^T, block tile 64x256,
// 4 waves (2m x 2n), K staged 32/step.  LDS rows padded to 40 bf16.
// AMODE: 0 = A bf16, 1 = A f32 row-softmax exp(x-max)*inv, 2 = A f32 hi/lo split
// BMODE: 0 = B bf16, 2 = B f32 hi/lo split
// ATOMIC: 0 = store with biases, 1 = atomicAdd
template<int AMODE, int BMODE, int ATOMIC>
__global__ LB void mfma_nt(const u16* __restrict__ Abf, const float* __restrict__ Af,
                           int lda, long aBS,
                           const u16* __restrict__ Bbf, const float* __restrict__ Bf,
                           int ldb, long bBS,
                           float* __restrict__ C, int ldc, long cBS,
                           int nsteps, int zdiv,
                           const float* __restrict__ biasM, long bmBS,
                           const float* __restrict__ biasN,
                           const float* __restrict__ rmax, const float* __restrict__ rsum,
                           long rsBS)
{
    __shared__ u16 As [64 * 40];
    __shared__ u16 As2[(AMODE == 2) ? 64 * 40 : 8];
    __shared__ u16 Bs [256 * 40];
    __shared__ u16 Bs2[(BMODE == 2) ? 256 * 40 : 8];
    __shared__ float s_max[64], s_inv[64];

    const int tid = threadIdx.x;
    const int z = blockIdx.z;
    const int b = z / zdiv, ks = z - b * zdiv;
    const int m0 = blockIdx.x * 64;
    const int n0 = blockIdx.y * 256;
    const long kbase = (long)ks * nsteps * 32;

    const u16*   Ab  = Abf ? Abf + (long)b * aBS : nullptr;
    const float* Afp = Af  ? Af  + (long)b * aBS : nullptr;
    const u16*   Bb  = Bbf ? Bbf + (long)b * bBS : nullptr;
    const float* Bfp = Bf  ? Bf  + (long)b * bBS : nullptr;
    float* Cb = C + (long)b * cBS;
    const float* bM = biasM ? biasM + (long)b * bmBS : nullptr;

    if (AMODE == 1) {
        if (tid < 64) {
            s_max[tid] = rmax[(long)b * rsBS + m0 + tid];
            s_inv[tid] = 1.0f / rsum[(long)b * rsBS + m0 + tid];
        }
    }

    const int lane = tid & 63, wid = tid >> 6;
    const int wm = wid >> 1, wn = wid & 1;
    const int lr = lane & 15, lk = (lane >> 4) * 8;
    f32x4 acc[2][8] = {};

    const int ar = tid >> 2, aseg = tid & 3;

    for (int it = 0; it < nsteps; ++it) {
        const long kk = kbase + (long)it * 32;
        __syncthreads();
        // ---- stage A: 64 rows x 32 elems
        if (AMODE == 0) {
            *(uint4*)&As[ar * 40 + aseg * 8] =
                *(const uint4*)(Ab + (long)(m0 + ar) * lda + kk + aseg * 8);
        } else if (AMODE == 2) {
            const float4* s = (const float4*)(Afp + (long)(m0 + ar) * lda + kk + aseg * 8);
            float4 x0 = s[0], x1 = s[1];
            float xs[8] = {x0.x, x0.y, x0.z, x0.w, x1.x, x1.y, x1.z, x1.w};
            u32 hw[4], lw[4];
            #pragma unroll
            for (int p = 0; p < 4; ++p) {
                u16 h0 = f2bf(xs[2*p]),   h1 = f2bf(xs[2*p+1]);
                u16 l0 = f2bf(xs[2*p]   - bf2f(h0));
                u16 l1 = f2bf(xs[2*p+1] - bf2f(h1));
                hw[p] = (u32)h0 | ((u32)h1 << 16);
                lw[p] = (u32)l0 | ((u32)l1 << 16);
            }
            uint4 th; th.x = hw[0]; th.y = hw[1]; th.z = hw[2]; th.w = hw[3];
            uint4 tl; tl.x = lw[0]; tl.y = lw[1]; tl.z = lw[2]; tl.w = lw[3];
            *(uint4*)&As [ar * 40 + aseg * 8] = th;
            *(uint4*)&As2[ar * 40 + aseg * 8] = tl;
        } else {
            const float4* s = (const float4*)(Afp + (long)(m0 + ar) * lda + kk + aseg * 8);
            float4 x0 = s[0], x1 = s[1];
            float xs[8] = {x0.x, x0.y, x0.z, x0.w, x1.x, x1.y, x1.z, x1.w};
            float mm = s_max[ar], iv = s_inv[ar];
            u32 hw[4];
            #pragma unroll
            for (int p = 0; p < 4; ++p) {
                u16 h0 = f2bf(__expf(xs[2*p]   - mm) * iv);
                u16 h1 = f2bf(__expf(xs[2*p+1] - mm) * iv);
                hw[p] = (u32)h0 | ((u32)h1 << 16);
            }
            uint4 th; th.x = hw[0]; th.y = hw[1]; th.z = hw[2]; th.w = hw[3];
            *(uint4*)&As[ar * 40 + aseg * 8] = th;
        }
        // ---- stage B: 256 rows x 32 elems, row n = tid
        if (BMODE == 0) {
            const uint4* s = (const uint4*)(Bb + (long)(n0 + tid) * ldb + kk);
            uint4* d = (uint4*)&Bs[tid * 40];
            d[0] = s[0]; d[1] = s[1]; d[2] = s[2]; d[3] = s[3];
        } else {
            const float4* s = (const float4*)(Bfp + (long)(n0 + tid) * ldb + kk);
            float xs[32];
            #pragma unroll
            for (int q = 0; q < 8; ++q) {
                float4 t = s[q];
                xs[4*q] = t.x; xs[4*q+1] = t.y; xs[4*q+2] = t.z; xs[4*q+3] = t.w;
            }
            u32 hw[16], lw[16];
            #pragma unroll
            for (int p = 0; p < 16; ++p) {
                u16 h0 = f2bf(xs[2*p]),   h1 = f2bf(xs[2*p+1]);
                u16 l0 = f2bf(xs[2*p]   - bf2f(h0));
                u16 l1 = f2bf(xs[2*p+1] - bf2f(h1));
                hw[p] = (u32)h0 | ((u32)h1 << 16);
                lw[p] = (u32)l0 | ((u32)l1 << 16);
            }
            uint4* dh = (uint4*)&Bs [tid * 40];
            uint4* dl = (uint4*)&Bs2[tid * 40];
            #pragma unroll
            for (int g = 0; g < 4; ++g) {
                uint4 t; t.x = hw[4*g]; t.y = hw[4*g+1]; t.z = hw[4*g+2]; t.w = hw[4*g+3];
                dh[g] = t;
                uint4 t2; t2.x = lw[4*g]; t2.y = lw[4*g+1]; t2.z = lw[4*g+2]; t2.w = lw[4*g+3];
                dl[g] = t2;
            }
        }
        __syncthreads();
        // ---- compute
        bf16x8 a0 = *(const bf16x8*)&As[(wm * 32 + lr) * 40 + lk];
        bf16x8 a1 = *(const bf16x8*)&As[(wm * 32 + 16 + lr) * 40 + lk];
        bf16x8 a0l, a1l;
        if (AMODE == 2) {
            a0l = *(const bf16x8*)&As2[(wm * 32 + lr) * 40 + lk];
            a1l = *(const bf16x8*)&As2[(wm * 32 + 16 + lr) * 40 + lk];
        }
        #pragma unroll
        for (int nt = 0; nt < 8; ++nt) {
            const int boff = (wn * 128 + nt * 16 + lr) * 40 + lk;
            bf16x8 bh = *(const bf16x8*)&Bs[boff];
            acc[0][nt] = MFMA(a0, bh, acc[0][nt]);
            acc[1][nt] = MFMA(a1, bh, acc[1][nt]);
            if (AMODE == 2 && BMODE == 2) {
                bf16x8 bl = *(const bf16x8*)&Bs2[boff];
                acc[0][nt] = MFMA(a0,  bl, acc[0][nt]);
                acc[0][nt] = MFMA(a0l, bh, acc[0][nt]);
                acc[1][nt] = MFMA(a1,  bl, acc[1][nt]);
                acc[1][nt] = MFMA(a1l, bh, acc[1][nt]);
            }
        }
    }
    // ---- epilogue.  D: col = lane&15, row = (lane>>4)*4 + reg
    const int cr = (lane >> 4) * 4;
    #pragma unroll
    for (int mt = 0; mt < 2; ++mt) {
        #pragma unroll
        for (int nt = 0; nt < 8; ++nt) {
            f32x4 a = acc[mt][nt];
            const long gm0 = m0 + wm * 32 + mt * 16 + cr;
            const int  gn  = n0 + wn * 128 + nt * 16 + lr;
            float bn = (!ATOMIC && biasN) ? biasN[gn] : 0.f;
            #pragma unroll
            for (int rr = 0; rr < 4; ++rr) {
                if (ATOMIC) {
                    atomicAdd(Cb + (gm0 + rr) * (long)ldc + gn, a[rr]);
                } else {
                    float bm = bM ? bM[gm0 + rr] : 0.f;
                    Cb[(gm0 + rr) * (long)ldc + gn] = a[rr] + bm + bn;
                }
            }
        }
    }
}

// ---------------------------------------------------------------------------
// f32 split-K NT GEMM with atomic accumulation (projections / out_l).
// C must be pre-zeroed.  z = ((b * nproj + p) * ksplit + ks).
__global__ LB void gemm_nt_sk(const float* __restrict__ A, int lda, long aZb,
                              const float* __restrict__ B0, const float* __restrict__ B1,
                              int ldb,
                              float* __restrict__ C0, float* __restrict__ C1,
                              int ldc, long cZb,
                              int kslice, int ksplit, int nproj,
                              const float* __restrict__ bN0, const float* __restrict__ bN1,
                              float scale)
{
    int z = blockIdx.z;
    const int ks = z % ksplit; z /= ksplit;
    const int p  = z % nproj;  z /= nproj;
    const int b  = z;
    const float* Bm = p ? B1 : B0;
    const float* bN = p ? bN1 : bN0;
    float* C = (p ? C1 : C0) + (long)b * cZb;
    const float* Ab = A + (long)b * aZb;
    const int m0 = blockIdx.y * 64, n0 = blockIdx.x * 64;
    const int k0 = ks * kslice;
    __shared__ float As[64][36];
    __shared__ float Bs[64][36];
    const int tid = threadIdx.x;
    const int tm = (tid >> 4) * 4, tn = tid & 15;
    float acc[4][4] = {};
    for (int kb = 0; kb < kslice; kb += 32) {
        __syncthreads();
        #pragma unroll
        for (int idx = tid; idx < 2048; idx += 256) {
            int r = idx >> 5, c = idx & 31;
            As[r][c] = Ab[(long)(m0 + r) * lda + k0 + kb + c];
            Bs[r][c] = Bm[(long)(n0 + r) * ldb + k0 + kb + c];
        }
        __syncthreads();
        #pragma unroll
        for (int kk = 0; kk < 32; kk += 4) {
            float4 a0 = *(const float4*)&As[tm + 0][kk];
            float4 a1 = *(const float4*)&As[tm + 1][kk];
            float4 a2 = *(const float4*)&As[tm + 2][kk];
            float4 a3 = *(const float4*)&As[tm + 3][kk];
            float4 b0 = *(const float4*)&Bs[tn +  0][kk];
            float4 b1 = *(const float4*)&Bs[tn + 16][kk];
            float4 b2 = *(const float4*)&Bs[tn + 32][kk];
            float4 b3 = *(const float4*)&Bs[tn + 48][kk];
#define NT_ROW(m, av) \
            acc[m][0] += av.x*b0.x + av.y*b0.y + av.z*b0.z + av.w*b0.w; \
            acc[m][1] += av.x*b1.x + av.y*b1.y + av.z*b1.z + av.w*b1.w; \
            acc[m][2] += av.x*b2.x + av.y*b2.y + av.z*b2.z + av.w*b2.w; \
            acc[m][3] += av.x*b3.x + av.y*b3.y + av.z*b3.z + av.w*b3.w;
            NT_ROW(0, a0) NT_ROW(1, a1) NT_ROW(2, a2) NT_ROW(3, a3)
#undef NT_ROW
        }
    }
    #pragma unroll
    for (int im = 0; im < 4; ++im) {
        #pragma unroll
        for (int q = 0; q < 4; ++q) {
            float vadd = scale * acc[im][q];
            if (ks == 0 && bN) vadd += bN[n0 + tn + 16*q];
            atomicAdd(&C[(long)(m0 + tm + im) * ldc + n0 + tn + 16*q], vadd);
        }
    }
}

// f32 split-K NT GEMM with per-(batch,head) offsets (UU).  C pre-zeroed.
// z = ((zb*4+zh)*ksplit + ks)
__global__ LB void gemm_nt_sk2(const float* __restrict__ A, int lda, long aZb, long aZh,
                               const float* __restrict__ Bm, int ldb, long bZb, long bZh,
                               float* __restrict__ C, int ldo, long oZb, long oZh,
                               int kslice, int ksplit, float scale)
{
    int z = blockIdx.z;
    const int ks = z % ksplit; z /= ksplit;
    const int zb = z >> 2, zh = z & 3;
    const int k0 = ks * kslice;
    A  += (long)zb * aZb + (long)zh * aZh + k0;
    Bm += (long)zb * bZb + (long)zh * bZh + k0;
    C  += (long)zb * oZb + (long)zh * oZh;
    const int m0 = blockIdx.y * 64, n0 = blockIdx.x * 64;
    __shared__ float As[64][36];
    __shared__ float Bs[64][36];
    const int tid = threadIdx.x;
    const int tm = (tid >> 4) * 4, tn = tid & 15;
    float acc[4][4] = {};
    for (int kb = 0; kb < kslice; kb += 32) {
        __syncthreads();
        #pragma unroll
        for (int idx = tid; idx < 2048; idx += 256) {
            int r = idx >> 5, c = idx & 31;
            As[r][c] = A[(long)(m0 + r) * lda + kb + c];
            Bs[r][c] = Bm[(long)(n0 + r) * ldb + kb + c];
        }
        __syncthreads();
        #pragma unroll
        for (int kk = 0; kk < 32; kk += 4) {
            float4 a0 = *(const float4*)&As[tm + 0][kk];
            float4 a1 = *(const float4*)&As[tm + 1][kk];
            float4 a2 = *(const float4*)&As[tm + 2][kk];
            float4 a3 = *(const float4*)&As[tm + 3][kk];
            float4 b0 = *(const float4*)&Bs[tn +  0][kk];
            float4 b1 = *(const float4*)&Bs[tn + 16][kk];
            float4 b2 = *(const float4*)&Bs[tn + 32][kk];
            float4 b3 = *(const float4*)&Bs[tn + 48][kk];
#define NT_ROW(m, av) \
            acc[m][0] += av.x*b0.x + av.y*b0.y + av.z*b0.z + av.w*b0.w; \
            acc[m][1] += av.x*b1.x + av.y*b1.y + av.z*b1.z + av.w*b1.w; \
            acc[m][2] += av.x*b2.x + av.y*b2.y + av.z*b2.z + av.w*b2.w; \
            acc[m][3] += av.x*b3.x + av.y*b3.y + av.z*b3.z + av.w*b3.w;
            NT_ROW(0, a0) NT_ROW(1, a1) NT_ROW(2, a2) NT_ROW(3, a3)
#undef NT_ROW
        }
    }
    #pragma unroll
    for (int im = 0; im < 4; ++im)
        #pragma unroll
        for (int q = 0; q < 4; ++q)
            atomicAdd(&C[(long)(m0 + tm + im) * ldo + n0 + tn + 16*q],
                      scale * acc[im][q]);
}

// f32 split-K NN GEMM with per-(batch,head) offsets (CM, W2).  C pre-zeroed.
__global__ LB void gemm_nn_sk(const float* __restrict__ A, int lda, long aZb, long aZh,
                              const float* __restrict__ Bm, int ldb, long bZb, long bZh,
                              float* __restrict__ C, int ldo, long oZb, long oZh,
                              int kslice, int ksplit, float scale)
{
    int z = blockIdx.z;
    const int ks = z % ksplit; z /= ksplit;
    const int zb = z >> 2, zh = z & 3;
    const int k0 = ks * kslice;
    A  += (long)zb * aZb + (long)zh * aZh + k0;
    Bm += (long)zb * bZb + (long)zh * bZh + (long)k0 * ldb;
    C  += (long)zb * oZb + (long)zh * oZh;
    const int m0 = blockIdx.y * 64, n0 = blockIdx.x * 64;
    __shared__ float As[64][36];
    __shared__ float Bs[32][68];
    const int tid = threadIdx.x;
    const int tm = (tid >> 4) * 4, tn = (tid & 15) * 4;
    float acc[4][4] = {};
    for (int kb = 0; kb < kslice; kb += 32) {
        __syncthreads();
        #pragma unroll
        for (int idx = tid; idx < 2048; idx += 256) {
            int r = idx >> 5, c = idx & 31;
            As[r][c] = A[(long)(m0 + r) * lda + kb + c];
            int r2 = idx >> 6, c2 = idx & 63;
            Bs[r2][c2] = Bm[(long)(kb + r2) * ldb + n0 + c2];
        }
        __syncthreads();
        #pragma unroll
        for (int kk = 0; kk < 32; kk += 4) {
            float4 a0 = *(const float4*)&As[tm + 0][kk];
            float4 a1 = *(const float4*)&As[tm + 1][kk];
            float4 a2 = *(const float4*)&As[tm + 2][kk];
            float4 a3 = *(const float4*)&As[tm + 3][kk];
            float4 b0 = *(const float4*)&Bs[kk + 0][tn];
            float4 b1 = *(const float4*)&Bs[kk + 1][tn];
            float4 b2 = *(const float4*)&Bs[kk + 2][tn];
            float4 b3 = *(const float4*)&Bs[kk + 3][tn];
#define NN_ROW(m, av) \
            acc[m][0] += av.x*b0.x + av.y*b1.x + av.z*b2.x + av.w*b3.x; \
            acc[m][1] += av.x*b0.y + av.y*b1.y + av.z*b2.y + av.w*b3.y; \
            acc[m][2] += av.x*b0.z + av.y*b1.z + av.z*b2.z + av.w*b3.z; \
            acc[m][3] += av.x*b0.w + av.y*b1.w + av.z*b2.w + av.w*b3.w;
            NN_ROW(0, a0) NN_ROW(1, a1) NN_ROW(2, a2) NN_ROW(3, a3)
#undef NN_ROW
        }
    }
    #pragma unroll
    for (int im = 0; im < 4; ++im) {
        atomicAdd(&C[(long)(m0 + tm + im) * ldo + n0 + tn + 0], scale * acc[im][0]);
        atomicAdd(&C[(long)(m0 + tm + im) * ldo + n0 + tn + 1], scale * acc[im][1]);
        atomicAdd(&C[(long)(m0 + tm + im) * ldo + n0 + tn + 2], scale * acc[im][2]);
        atomicAdd(&C[(long)(m0 + tm + im) * ldo + n0 + tn + 3], scale * acc[im][3]);
    }
}

// cbias[b][ht] = SCALE * sum_d vp_b[h*256+d] * KF[(b*64+t)*1024 + h*256+d]
__global__ LB void k_cbias(const float* __restrict__ KF, const float* __restrict__ vp_b,
                           float* __restrict__ cb)
{
    int idx = blockIdx.x * 256 + threadIdx.x;      // 0..1023
    int b = idx >> 8, ht = idx & 255, h = ht >> 6, t = ht & 63;
    const float* kr = KF + (long)(b * 64 + t) * 1024 + h * 256;
    const float* br = vp_b + h * 256;
    float s = 0.f;
    for (int d = 0; d < 256; d += 4) {
        float4 a = *(const float4*)&kr[d];
        float4 c = *(const float4*)&br[d];
        s += a.x*c.x + a.y*c.y + a.z*c.z + a.w*c.w;
    }
    cb[idx] = s * SC_;
}

// bias2[o] = olp_b[o] + sum_hd olp_w[o*1024+hd]*vvp_b[hd]
__global__ LB void k_bias2(const float* __restrict__ olp_w, const float* __restrict__ olp_b,
                           const float* __restrict__ vvp_b, float* __restrict__ b2)
{
    int o = blockIdx.x * 256 + threadIdx.x;        // 0..767
    const float* wr = olp_w + (long)o * 1024;
    float s = olp_b[o];
    for (int k = 0; k < 1024; k += 4) {
        float4 a = *(const float4*)&wr[k];
        float4 c = *(const float4*)&vvp_b[k];
        s += a.x*c.x + a.y*c.y + a.z*c.z + a.w*c.w;
    }
    b2[o] = s;
}

// transpose conv weights: Wt[(ti*9+tap)*64 + to] = down_w[((to*64+ti)*9 + tap)]
__global__ LB void k_wt(const float* __restrict__ dw, float* __restrict__ Wt)
{
    int idx = blockIdx.x * 256 + threadIdx.x;      // < 36864
    int to = idx / 576, rem = idx - to * 576;
    int ti = rem / 9, tap = rem - ti * 9;
    Wt[(ti * 9 + tap) * 64 + to] = dw[idx];
}

// stride-2 3x3 conv, 64ch->64ch (inputs are ORIGINAL aw levels 0..2)
__global__ LB void k_conv(const float* __restrict__ aw, const float* __restrict__ Wt,
                          const float* __restrict__ down_b, float* __restrict__ lo)
{
    __shared__ float ins[16][17][36];
    const int bx = blockIdx.x, bh = blockIdx.y;
    int w_out, w_in, in_off, lo_off, ty, tx;
    if (bx < 32)      { w_out = 64; w_in = 128; in_off = 0;     lo_off = 0;    ty = bx >> 2;       tx = bx & 3; }
    else if (bx < 40) { w_out = 32; w_in = 64;  in_off = 16384; lo_off = 4096; int e = bx - 32; ty = e >> 1; tx = e & 1; }
    else              { w_out = 16; w_in = 32;  in_off = 20480; lo_off = 5120; ty = bx - 40;       tx = 0; }
    const int y0 = ty * 8, x0 = tx * 16;
    const int tid = threadIdx.x;
    const int to0 = (tid & 15) * 4;
    const int pg = tid >> 4;
    const int py = pg & 7;
    const int xbase = (pg >> 3) * 8;
    const float* in_base = aw + (long)(bh >> 2) * HT_ * NI_ + (long)((bh & 3) * 64) * NI_ + in_off;
    float acc[4][8] = {};
    for (int tc = 0; tc < 64; tc += 16) {
        __syncthreads();
        for (int idx = tid; idx < 16 * 561; idx += 256) {
            int ti = idx / 561, rem = idx - ti * 561;
            int r = rem / 33, c = rem - r * 33;
            int gy = 2 * y0 - 1 + r, gx = 2 * x0 - 1 + c;
            float vv = 0.f;
            if (gy >= 0 && gy < w_in && gx >= 0 && gx < w_in)
                vv = in_base[(long)(tc + ti) * NI_ + gy * w_in + gx];
            ins[ti][r][c] = vv;
        }
        __syncthreads();
        for (int ti = 0; ti < 16; ++ti) {
            const int tig = tc + ti;
            #pragma unroll
            for (int ky = 0; ky < 3; ++ky) {
                const int r = 2 * py + ky;
                const float* rowp = &ins[ti][r][2 * xbase];
                float rv[20];
                #pragma unroll
                for (int q = 0; q < 5; ++q) {
                    float4 f = *(const float4*)(rowp + 4 * q);
                    rv[4*q+0] = f.x; rv[4*q+1] = f.y; rv[4*q+2] = f.z; rv[4*q+3] = f.w;
                }
                #pragma unroll
                for (int kx = 0; kx < 3; ++kx) {
                    float4 w4 = *(const float4*)&Wt[(tig * 9 + ky * 3 + kx) * 64 + to0];
                    #pragma unroll
                    for (int x = 0; x < 8; ++x) {
                        float iv = rv[2 * x + kx];
                        acc[0][x] += iv * w4.x;
                        acc[1][x] += iv * w4.y;
                        acc[2][x] += iv * w4.z;
                        acc[3][x] += iv * w4.w;
                    }
                }
            }
        }
    }
    const long lo_base = (long)bh * 64 * 5376;
    #pragma unroll
    for (int j = 0; j < 4; ++j) {
        float bias = down_b[to0 + j];
        float* op = lo + lo_base + (long)(to0 + j) * 5376 + lo_off + (y0 + py) * w_out + x0 + xbase;
        #pragma unroll
        for (int x = 0; x < 8; ++x) op[x] = acc[j][x] + bias;
    }
}

// in-place pyramid update for one level (launched lvl 0,1,2,3 in order)
__global__ LB void k_update(float* __restrict__ aw, const float* __restrict__ lo,
                            const float* __restrict__ simp, int lvl, int w_out, int off_out,
                            int w_src, int off_src, int lo_off)
{
    const int bht = blockIdx.y;
    const int pix = blockIdx.x * 256 + threadIdx.x;
    float* base = aw + (long)bht * NI_;
    float cur = base[off_out + pix];
    float alpha = simp[0];
    float upd = 0.f;
    if (lvl < 3) {
        int y = pix / w_out, x = pix - y * w_out;
        int j0 = (y - 1) >> 1; float wy = (y & 1) ? 0.25f : 0.75f;
        int i0 = (x - 1) >> 1; float wx = (x & 1) ? 0.25f : 0.75f;
        int j0c = j0 < 0 ? 0 : j0, j1c = j0 + 1 < w_src ? j0 + 1 : w_src - 1;
        int i0c = i0 < 0 ? 0 : i0, i1c = i0 + 1 < w_src ? i0 + 1 : w_src - 1;
        const float* src = base + off_src;
        float v00 = src[j0c * w_src + i0c], v01 = src[j0c * w_src + i1c];
        float v10 = src[j1c * w_src + i0c], v11 = src[j1c * w_src + i1c];
        float up = (1.f - wy) * ((1.f - wx) * v00 + wx * v01) + wy * ((1.f - wx) * v10 + wx * v11);
        upd += alpha * (up - cur);
    }
    if (lvl > 0) {
        float lov = lo[(long)bht * 5376 + lo_off + pix];
        upd += alpha * (lov - cur);
    }
    base[off_out + pix] = cur + 0.5f * upd;
}

// per-(b,ht) row max and sumexp over 21760 image positions (for p_l)
__global__ LB void k_colstats(const float* __restrict__ aw, float* __restrict__ cmax,
                              float* __restrict__ csum)
{
    const int bht = blockIdx.x;
    const float* row = aw + (long)bht * NI_;
    const int tid = threadIdx.x;
    float m = -3.0e38f, s = 0.f;
    for (int i = tid; i < NI_; i += 256) {
        float vv = row[i];
        if (vv > m) { s *= __expf(m - vv); m = vv; }
        s += __expf(vv - m);
    }
    for (int off = 32; off > 0; off >>= 1) {
        float om = __shfl_down(m, off, 64);
        float os = __shfl_down(s, off, 64);
        float M = fmaxf(m, om);
        s = s * __expf(m - M) + os * __expf(om - M);
        m = M;
    }
    __shared__ float sm[4], ss[4];
    int wave = tid >> 6;
    if ((tid & 63) == 0) { sm[wave] = m; ss[wave] = s; }
    __syncthreads();
    if (tid == 0) {
        m = sm[0]; s = ss[0];
        for (int w = 1; w < 4; ++w) {
            float M = fmaxf(m, sm[w]);
            s = s * __expf(m - M) + ss[w] * __expf(sm[w] - M);
            m = M;
        }
        cmax[bht] = m; csum[bht] = s;
    }
}

// v[b][i][c] f32 -> VBT[b][c][i] bf16  (64x64 LDS tile transpose)
__global__ LB void k_cvt_vt(const float* __restrict__ v, u16* __restrict__ VBT)
{
    const int b = blockIdx.z, i0 = blockIdx.x * 64, c0 = blockIdx.y * 64;
    __shared__ u16 Ts[64][72];
    const int tid = threadIdx.x;
    const int r = tid >> 2, seg = tid & 3;
    const float4* s = (const float4*)(v + ((long)b * NI_ + i0 + r) * 256 + c0 + seg * 16);
    #pragma unroll
    for (int q = 0; q < 4; ++q) {
        float4 x = s[q];
        Ts[r][seg * 16 + 4*q + 0] = f2bf(x.x);
        Ts[r][seg * 16 + 4*q + 1] = f2bf(x.y);
        Ts[r][seg * 16 + 4*q + 2] = f2bf(x.z);
        Ts[r][seg * 16 + 4*q + 3] = f2bf(x.w);
    }
    __syncthreads();
    const int cr = tid >> 2, is = tid & 3;
    u32 o[8];
    #pragma unroll
    for (int j = 0; j < 8; ++j)
        o[j] = (u32)Ts[is * 16 + 2*j][cr] | ((u32)Ts[is * 16 + 2*j + 1][cr] << 16);
    uint4* d = (uint4*)(VBT + ((long)b * 256 + c0 + cr) * NI_ + i0 + is * 16);
    uint4 t0; t0.x = o[0]; t0.y = o[1]; t0.z = o[2]; t0.w = o[3];
    uint4 t1; t1.x = o[4]; t1.y = o[5]; t1.z = o[6]; t1.w = o[7];
    d[0] = t0; d[1] = t1;
}

// U[b][ht][o] f32 -> UT[b][o][ht] bf16
__global__ LB void k_t_u(const float* __restrict__ U, u16* __restrict__ UT)
{
    const int b = blockIdx.z, r0 = blockIdx.x * 64, c0 = blockIdx.y * 64;
    __shared__ float Fs[64][68];
    const int tid = threadIdx.x;
    const int r = tid >> 2, seg = tid & 3;
    const float4* s = (const float4*)(U + ((long)b * 256 + r0 + r) * 256 + c0 + seg * 16);
    #pragma unroll
    for (int q = 0; q < 4; ++q) *(float4*)&Fs[r][seg * 16 + 4*q] = s[q];
    __syncthreads();
    const int cr = tid >> 2, is = tid & 3;
    u32 o[8];
    #pragma unroll
    for (int j = 0; j < 8; ++j)
        o[j] = (u32)f2bf(Fs[is * 16 + 2*j][cr]) | ((u32)f2bf(Fs[is * 16 + 2*j + 1][cr]) << 16);
    uint4* d = (uint4*)(UT + ((long)b * 256 + c0 + cr) * 256 + r0 + is * 16);
    uint4 t0; t0.x = o[0]; t0.y = o[1]; t0.z = o[2]; t0.w = o[3];
    uint4 t1; t1.x = o[4]; t1.y = o[5]; t1.z = o[6]; t1.w = o[7];
    d[0] = t0; d[1] = t1;
}

// PV[b][i][ht] bf16 = softmax over t (within head) of AW[b][ht][i].
// i-tile 64, coalesced loads (16 thr/row), all 256 threads do softmax.
// tile[256][64] = 64 KB LDS; column reads have unit lane-stride -> conflict-free.
__global__ LB void k_pv(const float* __restrict__ aw, u16* __restrict__ PV)
{
    const int b = blockIdx.y;
    const int i0 = blockIdx.x * 64;
    const int tid = threadIdx.x;
    __shared__ float tile[256][64];
    const float* awb = aw + (long)b * HT_ * NI_ + i0;
    for (int idx = tid; idx < 4096; idx += 256) {
        int r = idx >> 4, c4 = (idx & 15) * 4;
        *(float4*)&tile[r][c4] = *(const float4*)(awb + (long)r * NI_ + c4);
    }
    __syncthreads();
    const int h = tid >> 6, i = tid & 63;
    float m = -3.0e38f;
    #pragma unroll 8
    for (int t = 0; t < 64; ++t) m = fmaxf(m, tile[h * 64 + t][i]);
    float s = 0.f;
    #pragma unroll 8
    for (int t = 0; t < 64; ++t) {
        float e = __expf(tile[h * 64 + t][i] - m);
        tile[h * 64 + t][i] = e;       // only this thread touches column i of this h-group
        s += e;
    }
    float inv = 1.f / s;
    u32* dst = (u32*)(PV + ((long)b * NI_ + i0 + i) * 256 + h * 64);
    #pragma unroll 8
    for (int t = 0; t < 32; ++t) {
        u16 p0 = f2bf(tile[h * 64 + 2*t][i] * inv);
        u16 p1 = f2bf(tile[h * 64 + 2*t + 1][i] * inv);
        dst[t] = (u32)p0 | ((u32)p1 << 16);
    }
}

// G2[b][t][h*256+c] = G[b][h*64+t][c]
__global__ LB void k_g2t(const float* __restrict__ G, float* __restrict__ G2)
{
    int idx = blockIdx.x * 256 + threadIdx.x;   // < 262144
    int b = idx >> 16, r = idx & 65535;
    int t = r >> 10, e = r & 1023;
    int h = e >> 8, c = e & 255;
    G2[idx] = G[(long)b * 65536 + (h * 64 + t) * 256 + c];
}

// ---------------------------------------------------------------------------
extern "C" void kernel_launch(void* const* d_in, const int* in_sizes, int n_in,
                              void* d_out, int out_size, void* d_ws, size_t ws_size,
                              hipStream_t stream)
{
    const float* v      = (const float*)d_in[0];
    const float* l      = (const float*)d_in[1];
    const float* simp   = (const float*)d_in[2];
    const float* vp_w   = (const float*)d_in[3];
    const float* vp_b   = (const float*)d_in[4];
    const float* lp_w   = (const float*)d_in[5];
    const float* lp_b   = (const float*)d_in[6];
    const float* vvp_w  = (const float*)d_in[7];
    const float* vvp_b  = (const float*)d_in[8];
    const float* vlp_w  = (const float*)d_in[9];
    const float* vlp_b  = (const float*)d_in[10];
    const float* ovp_w  = (const float*)d_in[11];
    const float* ovp_b  = (const float*)d_in[12];
    const float* olp_w  = (const float*)d_in[13];
    const float* olp_b  = (const float*)d_in[14];
    const float* down_w = (const float*)d_in[15];
    const float* down_b = (const float*)d_in[16];

    float* outv = (float*)d_out;
    float* outl = outv + OUTV_N;
    float* AW   = outv;                 // AW lives in the outv region (dead before attnv writes)
    float* ws = (float*)d_ws;
    float* KF  = ws + WS_KF;
    float* VL  = ws + WS_VL;
    float* CM  = ws + WS_CM;
    float* CB  = ws + WS_CB;
    float* UU  = ws + WS_UU;
    float* W2  = ws + WS_W2;
    float* B2  = ws + WS_B2;
    float* WT  = ws + WS_WT;
    float* CMX = ws + WS_CMX;
    float* CSM = ws + WS_CSM;
    float* G   = ws + WS_G;
    float* G2  = ws + WS_G2;
    u16*   UT  = (u16*)(ws + WS_UT);
    float* LO  = ws + WS_SH;            // phase A
    u16*   VBT = (u16*)(ws + WS_SH);    // phase B (after updates)
    u16*   PV  = (u16*)(ws + WS_SH);    // phase C (after plv)

    // 0: zero split-K accumulation targets
    hipMemsetAsync(KF, 0, 524288 * sizeof(float), stream);             // KF+VL
    hipMemsetAsync(CM, 0, (WS_B2 - WS_CM) * sizeof(float), stream);    // CM+CB+UU+W2
    hipMemsetAsync(outl, 0, 196608 * sizeof(float), stream);
    hipMemsetAsync(G, 0, 262144 * sizeof(float), stream);

    // 1: projections KF = l@lp_w.T+lp_b, VL = l@vlp_w.T+vlp_b  (fused, split-K x3)
    gemm_nt_sk<<<dim3(16, 4, 6), 256, 0, stream>>>(l, 768, 0, lp_w, vlp_w, 768,
                                                   KF, VL, 1024, 0,
                                                   256, 3, 2, lp_b, vlp_b, 1.f);
    // 2: small folded mats (split-K x4 / x2, atomic)
    gemm_nn_sk<<<dim3(4, 1, 64), 256, 0, stream>>>(KF, 1024, 65536, 256,
                                                   vp_w, 256, 0, 65536,
                                                   CM, 256, 65536, 16384, 64, 4, SC_);
    k_cbias<<<dim3(4), 256, 0, stream>>>(KF, vp_b, CB);
    gemm_nt_sk2<<<dim3(4, 1, 64), 256, 0, stream>>>(VL, 1024, 65536, 256,
                                                    ovp_w, 1024, 0, 256,
                                                    UU, 256, 65536, 16384, 64, 4, 1.f);
    gemm_nn_sk<<<dim3(4, 12, 8), 256, 0, stream>>>(olp_w, 1024, 0, 256,
                                                   vvp_w, 256, 0, 65536,
                                                   W2, 1024, 0, 256, 128, 2, 1.f);
    k_bias2<<<dim3(3), 256, 0, stream>>>(olp_w, olp_b, vvp_b, B2);
    k_t_u<<<dim3(4, 4, 4), 256, 0, stream>>>(UU, UT);

    // 3: AW = CM @ v^T + cbias  (bf16x3 split MFMA; M=256, N=21760, K=256)
    mfma_nt<2, 2, 0><<<dim3(4, 85, 4), 256, 0, stream>>>(
        nullptr, CM, 256, 65536,
        nullptr, v, 256, (long)NI_ * 256,
        AW, NI_, (long)HT_ * NI_,
        8, 1, CB, 256, nullptr, nullptr, nullptr, 0);

    // 4: conv downsample + in-place pyramid update
    k_wt<<<dim3(144), 256, 0, stream>>>(down_w, WT);
    k_conv<<<dim3(42, 16), 256, 0, stream>>>(AW, WT, down_b, LO);
    k_update<<<dim3(64, 1024), 256, 0, stream>>>(AW, LO, simp, 0, 128, 0,     64, 16384, 0);
    k_update<<<dim3(16, 1024), 256, 0, stream>>>(AW, LO, simp, 1, 64, 16384,  32, 20480, 0);
    k_update<<<dim3(4, 1024), 256, 0, stream>>>(AW, LO, simp, 2, 32, 20480,  16, 21504, 4096);
    k_update<<<dim3(1, 1024), 256, 0, stream>>>(AW, LO, simp, 3, 16, 21504,   0, 0,     5120);

    // 5: column-softmax stats over i per (b,ht)
    k_colstats<<<dim3(1024), 256, 0, stream>>>(AW, CMX, CSM);

    // 6: v^T bf16 (overwrites LO region — LO is dead)
    k_cvt_vt<<<dim3(340, 4, 4), 256, 0, stream>>>(v, VBT);

    // 7: G = p_l @ v   (softmax-in-staging MFMA, split-K x17 with atomics)
    mfma_nt<1, 0, 1><<<dim3(4, 1, 68), 256, 0, stream>>>(
        nullptr, AW, NI_, (long)HT_ * NI_,
        VBT, nullptr, NI_, (long)256 * NI_,
        G, 256, 65536,
        40, 17, nullptr, 0, nullptr, CMX, CSM, 256);

    // 8: PV bf16 (overwrites VBT region — VBT is dead)
    k_pv<<<dim3(340, 4), 256, 0, stream>>>(AW, PV);

    // 9: out_v = PV @ UT^T + ovp_b  (MFMA; overwrites the AW/outv region)
    mfma_nt<0, 0, 0><<<dim3(340, 1, 4), 256, 0, stream>>>(
        PV, nullptr, 256, (long)NI_ * 256,
        UT, nullptr, 256, 65536,
        outv, 256, (long)NI_ * 256,
        8, 1, nullptr, 0, ovp_b, nullptr, nullptr, 0);

    // 10: out_l = G2 @ W2^T + bias2  (split-K x4 atomic)
    k_g2t<<<dim3(1024), 256, 0, stream>>>(G, G2);
    gemm_nt_sk<<<dim3(12, 1, 16), 256, 0, stream>>>(G2, 1024, 65536, W2, nullptr, 1024,
                                                    outl, nullptr, 768, 49152,
                                                    256, 4, 1, B2, nullptr, 1.f);
}